// Round 3
// baseline (424.421 us; speedup 1.0000x reference)
//
#include <hip/hip_runtime.h>
#include <math.h>

// GlobalSphereAttention: LN -> QKV -> per-head dots * scale * (1+sph)
//   -> cross-head mean/std(ddof=1) normalize -> softmax(j) -> PV -> out proj.
// B=2, N=2048, DIM=512, HEADS=8, DHEAD=64.
// Round 3: split-j flash attention (runtime SPLIT from ws_size) + coalesced
// V-plane writes + LDS transpose kernel + combine kernel.

typedef __attribute__((ext_vector_type(8))) short bf16x8;
typedef __attribute__((ext_vector_type(8))) unsigned short u16x8;
typedef __attribute__((ext_vector_type(4))) float f32x4;

constexpr int kDim = 512;
constexpr int kN = 2048;
constexpr float kEps = 1e-5f;
constexpr float kScale = 0.125f; // 64^-0.5

// ws layout (byte offsets)
constexpr size_t OFF_QHI  = 0;
constexpr size_t OFF_QLO  = 4u << 20;
constexpr size_t OFF_KHI  = 8u << 20;
constexpr size_t OFF_KLO  = 12u << 20;
constexpr size_t OFF_VTHI = 16u << 20;  // transposed [bh][d][n]
constexpr size_t OFF_VTLO = 20u << 20;
constexpr size_t OFF_VNHI = 24u << 20;  // natural [bh][n][d] (dead after vtrans)
constexpr size_t OFF_VNLO = 28u << 20;
constexpr size_t OFF_ML   = 33u << 20;  // float2 [s][bh16][n]  (<=2MB)
constexpr size_t OFF_MU   = 35u << 20;
constexpr size_t OFF_RS   = (35u << 20) + (64u << 10);
constexpr size_t OFF_AO_BIG   = 36u << 20;  // 8.4MB
constexpr size_t OFF_AO_SMALL = 24u << 20;  // aliases VN planes (dead by then)
constexpr size_t OFF_OP1  = 45u << 20;      // + (s-1)*9MB for s=1..3

__device__ __forceinline__ unsigned short bf16_rne(float f) {
  unsigned int u = __float_as_uint(f);
  u += 0x7fffu + ((u >> 16) & 1u);
  return (unsigned short)(u >> 16);
}
__device__ __forceinline__ float bf16f(unsigned short h) {
  return __uint_as_float(((unsigned int)h) << 16);
}
__device__ __forceinline__ f32x4 mfma16(bf16x8 a, bf16x8 b, f32x4 c) {
  return __builtin_amdgcn_mfma_f32_16x16x32_bf16(a, b, c, 0, 0, 0);
}

// ---------------- K1: LayerNorm row stats ----------------
__global__ __launch_bounds__(256) void k_ln_stats(const float* __restrict__ x,
                                                  float* __restrict__ mu,
                                                  float* __restrict__ rs) {
  int row = blockIdx.x * 4 + (threadIdx.x >> 6);
  int lane = threadIdx.x & 63;
  const float4* xr = (const float4*)(x + (size_t)row * kDim + lane * 8);
  float4 a = xr[0], b = xr[1];
  float s = a.x + a.y + a.z + a.w + b.x + b.y + b.z + b.w;
  float q = a.x*a.x + a.y*a.y + a.z*a.z + a.w*a.w
          + b.x*b.x + b.y*b.y + b.z*b.z + b.w*b.w;
#pragma unroll
  for (int off = 32; off > 0; off >>= 1) {
    s += __shfl_down(s, off);
    q += __shfl_down(q, off);
  }
  if (lane == 0) {
    float m = s * (1.0f / kDim);
    float v = q * (1.0f / kDim) - m * m;
    mu[row] = m;
    rs[row] = 1.0f / sqrtf(v + kEps);
  }
}

// ---------------- K2: fused-LN QKV GEMM, epilogue -> bf16 hi/lo planes ------
__global__ __launch_bounds__(256) void k_gemm_qkv(const float* __restrict__ x,
    const float* __restrict__ mu, const float* __restrict__ rs,
    const float* __restrict__ g, const float* __restrict__ bta,
    const float* __restrict__ w,
    unsigned short* __restrict__ qhi, unsigned short* __restrict__ qlo,
    unsigned short* __restrict__ khi, unsigned short* __restrict__ klo,
    unsigned short* __restrict__ vnhi, unsigned short* __restrict__ vnlo) {
  __shared__ float As[16][68];  // A^T tile (k-major)
  __shared__ float Bs[16][68];
  const int t = threadIdx.x;
  const int colBase = blockIdx.x * 64;
  const int rowBase = blockIdx.y * 64;
  const int ti = t >> 4, tj = t & 15;
  const int ar = t >> 2, ak = (t & 3) * 4;
  const int bk = t >> 4, bc = (t & 15) * 4;
  const int arow = rowBase + ar;
  const float amu = mu[arow], ars = rs[arow];
  float acc[4][4] = {};
  for (int kt = 0; kt < kDim; kt += 16) {
    float4 av = *(const float4*)(x + (size_t)arow * kDim + kt + ak);
    float4 gv = *(const float4*)(g + kt + ak);
    float4 bv = *(const float4*)(bta + kt + ak);
    float4 wv = *(const float4*)(w + (size_t)(kt + bk) * 1536 + colBase + bc);
    As[ak + 0][ar] = (av.x - amu) * ars * gv.x + bv.x;
    As[ak + 1][ar] = (av.y - amu) * ars * gv.y + bv.y;
    As[ak + 2][ar] = (av.z - amu) * ars * gv.z + bv.z;
    As[ak + 3][ar] = (av.w - amu) * ars * gv.w + bv.w;
    *(float4*)&Bs[bk][bc] = wv;
    __syncthreads();
#pragma unroll
    for (int kk = 0; kk < 16; ++kk) {
      float4 a4 = *(const float4*)&As[kk][ti * 4];
      float4 b4 = *(const float4*)&Bs[kk][tj * 4];
      float aa[4] = {a4.x, a4.y, a4.z, a4.w};
      float bb2[4] = {b4.x, b4.y, b4.z, b4.w};
#pragma unroll
      for (int r = 0; r < 4; ++r)
#pragma unroll
        for (int c = 0; c < 4; ++c)
          acc[r][c] += aa[r] * bb2[c];
    }
    __syncthreads();
  }
  const int col0 = colBase + tj * 4;
  const int which = col0 >> 9;
  const int cc = col0 & 511;
  const int h = cc >> 6, d = cc & 63;
  unsigned short* ph = (which == 0) ? qhi : ((which == 1) ? khi : vnhi);
  unsigned short* pl = (which == 0) ? qlo : ((which == 1) ? klo : vnlo);
#pragma unroll
  for (int r = 0; r < 4; ++r) {
    int row = rowBase + ti * 4 + r;
    int bI = row >> 11, n = row & 2047;
    size_t base = ((size_t)(bI * 8 + h) * kN + n) * 64 + d;
    unsigned short hv[4], lv[4];
#pragma unroll
    for (int c = 0; c < 4; ++c) {
      hv[c] = bf16_rne(acc[r][c]);
      lv[c] = bf16_rne(acc[r][c] - bf16f(hv[c]));
    }
    *(ushort4*)(ph + base) = make_ushort4(hv[0], hv[1], hv[2], hv[3]);
    *(ushort4*)(pl + base) = make_ushort4(lv[0], lv[1], lv[2], lv[3]);
  }
}

// ---------------- K2b: V transpose [bh][n][64] -> [bh][d][n] ----------------
__global__ __launch_bounds__(256) void k_vtrans(
    const unsigned short* __restrict__ vnhi, const unsigned short* __restrict__ vnlo,
    unsigned short* __restrict__ vthi, unsigned short* __restrict__ vtlo) {
  __shared__ unsigned short tile[64][72];  // 72: row stride 144B (16B-mult)
  const int id = blockIdx.x;
  const int p = id >> 9;
  const int bh = (id >> 5) & 15;
  const int nt = id & 31;
  const unsigned short* src = (p ? vnlo : vnhi) + ((size_t)bh * kN + nt * 64) * 64;
  unsigned short* dst = (p ? vtlo : vthi) + (size_t)bh * 64 * kN + nt * 64;
  const int r = threadIdx.x >> 3;
  const int c = (threadIdx.x & 7) * 8;
#pragma unroll
  for (int rr = 0; rr < 64; rr += 32) {
    u16x8 v = *(const u16x8*)(src + (size_t)(r + rr) * 64 + c);
    *(u16x8*)&tile[r + rr][c] = v;
  }
  __syncthreads();
#pragma unroll
  for (int dd = 0; dd < 64; dd += 32) {
    int d = r + dd;
    u16x8 v;
#pragma unroll
    for (int e = 0; e < 8; ++e) v[e] = tile[c + e][d];
    *(u16x8*)(dst + (size_t)d * kN + c) = v;
  }
}

// ---------------- K3: fused sphere attention, MFMA hi/lo, split-j -----------
// grid = S * 256 blocks x 512 threads. wave = head. block: 16 q-rows, j-range.
__global__ __launch_bounds__(512) void k_attn(
    const unsigned short* __restrict__ qhi, const unsigned short* __restrict__ qlo,
    const unsigned short* __restrict__ khi, const unsigned short* __restrict__ klo,
    const unsigned short* __restrict__ vthi, const unsigned short* __restrict__ vtlo,
    const float* __restrict__ sph,
    float* __restrict__ op0, float* __restrict__ op1,
    float* __restrict__ op2, float* __restrict__ op3,
    float2* __restrict__ ml, int jLen) {
  constexpr int STR = 68;          // dwords per score row (conflict-free)
  constexpr int STRH = 16 * STR;   // dwords per head
  __shared__ float Ss[8 * STRH];   // 34.8 KB, also holds packed P (u32)
  __shared__ float Fbuf[8][16];

  const int t = threadIdx.x;
  const int h = t >> 6;
  const int lane = t & 63;
  const int col = lane & 15;
  const int g = lane >> 4;
  const int tileId = blockIdx.x & 255;
  const int sId = blockIdx.x >> 8;
  const int bI = tileId >> 7;
  const int i0 = (tileId & 127) << 4;
  const int jStart = sId * jLen;
  const int jEnd = jStart + jLen;
  const size_t bh = (size_t)bI * 8 + h;
  float* opart = (sId == 0) ? op0 : ((sId == 1) ? op1 : ((sId == 2) ? op2 : op3));

  // Q fragments (A-frag: row=lane&15, k=d=g*8+e), hi/lo, chunks d0=0,32
  const size_t qoff = (bh * kN + i0 + col) * 64 + g * 8;
  const bf16x8 qh0 = *(const bf16x8*)(qhi + qoff);
  const bf16x8 qh1 = *(const bf16x8*)(qhi + qoff + 32);
  const bf16x8 ql0 = *(const bf16x8*)(qlo + qoff);
  const bf16x8 ql1 = *(const bf16x8*)(qlo + qoff + 32);

  const unsigned short* kb_hi = khi + (bh * kN + col) * 64 + g * 8;
  const unsigned short* kb_lo = klo + (bh * kN + col) * 64 + g * 8;
  const unsigned short* vb_hi = vthi + (bh * 64 + col) * kN + g * 8;
  const unsigned short* vb_lo = vtlo + (bh * 64 + col) * kN + g * 8;

  // prologue: K frags for first tile (B-frag: col=j, k=d=g*8+e)
  bf16x8 kh[8], kl[8];
#pragma unroll
  for (int jf = 0; jf < 4; ++jf)
#pragma unroll
    for (int c = 0; c < 2; ++c) {
      kh[jf * 2 + c] = *(const bf16x8*)(kb_hi + ((size_t)jStart + jf * 16) * 64 + c * 32);
      kl[jf * 2 + c] = *(const bf16x8*)(kb_lo + ((size_t)jStart + jf * 16) * 64 + c * 32);
    }

  f32x4 oacc[4];
#pragma unroll
  for (int nf = 0; nf < 4; ++nf) oacc[nf] = (f32x4){0.f, 0.f, 0.f, 0.f};
  float mreg = -INFINITY, lreg = 0.f;

  const int si = col;   // softmax row
  const int sp = g;     // softmax j-part
  const float* srow = &Ss[h * STRH + si * STR + sp * 16];
  unsigned int* sb32 = (unsigned int*)Ss;
  const int swz = (si & 3) * 8;

  for (int j0 = jStart; j0 < jEnd; j0 += 64) {
    // ---- QK^T: S = Qhi Khi + Qlo Khi + Qhi Klo ----
    f32x4 sacc[4];
#pragma unroll
    for (int jf = 0; jf < 4; ++jf) {
      f32x4 a = (f32x4){0.f, 0.f, 0.f, 0.f};
      a = mfma16(qh0, kh[jf * 2 + 0], a);
      a = mfma16(qh1, kh[jf * 2 + 1], a);
      a = mfma16(ql0, kh[jf * 2 + 0], a);
      a = mfma16(ql1, kh[jf * 2 + 1], a);
      a = mfma16(qh0, kl[jf * 2 + 0], a);
      a = mfma16(qh1, kl[jf * 2 + 1], a);
      sacc[jf] = a;
    }
    // ---- issue V loads early (land during norm/softmax) ----
    bf16x8 vh[8], vl[8];
#pragma unroll
    for (int nf = 0; nf < 4; ++nf)
#pragma unroll
      for (int c = 0; c < 2; ++c) {
        vh[nf * 2 + c] = *(const bf16x8*)(vb_hi + (size_t)(nf * 16) * kN + j0 + c * 32);
        vl[nf * 2 + c] = *(const bf16x8*)(vb_lo + (size_t)(nf * 16) * kN + j0 + c * 32);
      }
    // ---- S -> LDS (C/D: col=lane&15=j, row=g*4+r=i); conflict-free @STR=68 ----
#pragma unroll
    for (int jf = 0; jf < 4; ++jf)
#pragma unroll
      for (int r = 0; r < 4; ++r)
        Ss[h * STRH + (g * 4 + r) * STR + jf * 16 + col] = sacc[jf][r];
    __syncthreads();
    // ---- cross-head normalization (all 512 threads, 2 (i,j) pairs each) ----
    {
      const int jn = t & 63;
      const int ib = t >> 6;
#pragma unroll
      for (int half = 0; half < 2; ++half) {
        const int ii = ib + half * 8;
        float mult = kScale * (1.0f + sph[(size_t)(i0 + ii) * kN + j0 + jn]);
        float d8[8];
        float sum = 0.f;
#pragma unroll
        for (int hh = 0; hh < 8; ++hh) {
          d8[hh] = Ss[hh * STRH + ii * STR + jn] * mult;
          sum += d8[hh];
        }
        float mean = sum * 0.125f;
        float var = 0.f;
#pragma unroll
        for (int hh = 0; hh < 8; ++hh) {
          float dd = d8[hh] - mean;
          var += dd * dd;
        }
        float inv = rsqrtf(var * (1.0f / 7.0f));
#pragma unroll
        for (int hh = 0; hh < 8; ++hh)
          Ss[hh * STRH + ii * STR + jn] = (d8[hh] - mean) * inv;
      }
    }
    __syncthreads();
    // ---- online softmax (own head; lane: row si, j-part sp) ----
    {
      float vals[16];
      float4 dv;
      dv = *(const float4*)(srow + 0);  vals[0]=dv.x; vals[1]=dv.y; vals[2]=dv.z; vals[3]=dv.w;
      dv = *(const float4*)(srow + 4);  vals[4]=dv.x; vals[5]=dv.y; vals[6]=dv.z; vals[7]=dv.w;
      dv = *(const float4*)(srow + 8);  vals[8]=dv.x; vals[9]=dv.y; vals[10]=dv.z; vals[11]=dv.w;
      dv = *(const float4*)(srow + 12); vals[12]=dv.x; vals[13]=dv.y; vals[14]=dv.z; vals[15]=dv.w;
      float mx = vals[0];
#pragma unroll
      for (int q = 1; q < 16; ++q) mx = fmaxf(mx, vals[q]);
      mx = fmaxf(mx, __shfl_xor(mx, 16));
      mx = fmaxf(mx, __shfl_xor(mx, 32));
      float Mn = fmaxf(mreg, mx);
      float f = __expf(mreg - Mn);
      float s = 0.f;
      float pvv[16];
#pragma unroll
      for (int q = 0; q < 16; ++q) {
        pvv[q] = __expf(vals[q] - Mn);
        s += pvv[q];
      }
      s += __shfl_xor(s, 16);
      s += __shfl_xor(s, 32);
      lreg = lreg * f + s;
      mreg = Mn;
      if (g == 0) Fbuf[h][si] = f;
      // pack P as (hi | lo<<16), store with XOR-8(i&3) swizzle (in place)
#pragma unroll
      for (int qq = 0; qq < 4; ++qq) {
        unsigned int pk[4];
#pragma unroll
        for (int e = 0; e < 4; ++e) {
          float p = pvv[qq * 4 + e];
          unsigned short hi2 = bf16_rne(p);
          unsigned short lo2 = bf16_rne(p - bf16f(hi2));
          pk[e] = (unsigned int)hi2 | ((unsigned int)lo2 << 16);
        }
        *(uint4*)(sb32 + h * STRH + si * STR + ((sp * 16 + qq * 4) ^ swz)) =
            make_uint4(pk[0], pk[1], pk[2], pk[3]);
      }
    }
    // ---- PV (same wave only -> no barrier): A=P hi/lo, B=V hi/lo ----
    bf16x8 ph[2], pl[2];
#pragma unroll
    for (int c = 0; c < 2; ++c) {
      const int base = h * STRH + col * STR + (c * 32 + 8 * (g ^ (col & 3)));
      uint4 u0 = *(const uint4*)((const unsigned int*)Ss + base);
      uint4 u1 = *(const uint4*)((const unsigned int*)Ss + base + 4);
      unsigned int uu[8] = {u0.x, u0.y, u0.z, u0.w, u1.x, u1.y, u1.z, u1.w};
      bf16x8 h8, l8;
#pragma unroll
      for (int e = 0; e < 8; ++e) {
        h8[e] = (short)(uu[e] & 0xffffu);
        l8[e] = (short)(uu[e] >> 16);
      }
      ph[c] = h8;
      pl[c] = l8;
    }
    float fr[4];
#pragma unroll
    for (int r = 0; r < 4; ++r) fr[r] = Fbuf[h][g * 4 + r];
#pragma unroll
    for (int nf = 0; nf < 4; ++nf) {
      f32x4 a = oacc[nf];
#pragma unroll
      for (int r = 0; r < 4; ++r) a[r] *= fr[r];
      a = mfma16(ph[0], vh[nf * 2 + 0], a);
      a = mfma16(ph[1], vh[nf * 2 + 1], a);
      a = mfma16(pl[0], vh[nf * 2 + 0], a);
      a = mfma16(pl[1], vh[nf * 2 + 1], a);
      a = mfma16(ph[0], vl[nf * 2 + 0], a);
      a = mfma16(ph[1], vl[nf * 2 + 1], a);
      oacc[nf] = a;
    }
    // ---- prefetch next K tile ----
    if (j0 + 64 < jEnd) {
      const size_t joff = (size_t)(j0 + 64) * 64;
#pragma unroll
      for (int jf = 0; jf < 4; ++jf)
#pragma unroll
        for (int c = 0; c < 2; ++c) {
          kh[jf * 2 + c] = *(const bf16x8*)(kb_hi + joff + (size_t)(jf * 16) * 64 + c * 32);
          kl[jf * 2 + c] = *(const bf16x8*)(kb_lo + joff + (size_t)(jf * 16) * 64 + c * 32);
        }
    }
  }
  // ---- epilogue: unnormalized O + (m,l) ----
  if (g == 0)
    ml[((size_t)sId * 16 + bI * 8 + h) * kN + (i0 + si)] = make_float2(mreg, lreg);
#pragma unroll
  for (int r = 0; r < 4; ++r) {
    float* dst = opart + ((size_t)bI * kN + i0 + g * 4 + r) * 512 + h * 64;
#pragma unroll
    for (int nf = 0; nf < 4; ++nf)
      dst[nf * 16 + col] = oacc[nf][r];
  }
}

// ---------------- K3b: combine split partials -> AO ----------------
__global__ __launch_bounds__(256) void k_combine(
    const float* __restrict__ op0, const float* __restrict__ op1,
    const float* __restrict__ op2, const float* __restrict__ op3,
    const float2* __restrict__ ml, int S, float* __restrict__ ao) {
  const size_t e = ((size_t)blockIdx.x * 256 + threadIdx.x) * 4;
  const int row = (int)(e >> 9);
  const int col = (int)(e & 511);
  const int h = col >> 6;
  const int bI = row >> 11;
  const int n = row & 2047;
  const size_t mlBase = (size_t)(bI * 8 + h) * kN + n;
  float m0 = ml[mlBase].x;
  float ms = m0;
  if (S > 1) ms = fmaxf(ms, ml[(size_t)16 * kN + mlBase].x);
  if (S > 2) {
    ms = fmaxf(ms, ml[(size_t)32 * kN + mlBase].x);
    ms = fmaxf(ms, ml[(size_t)48 * kN + mlBase].x);
  }
  const float* ops[4] = {op0, op1, op2, op3};
  float L = 0.f;
  float4 acc = make_float4(0.f, 0.f, 0.f, 0.f);
  for (int s = 0; s < S; ++s) {
    float2 v = ml[(size_t)s * 16 * kN + mlBase];
    float wgt = __expf(v.x - ms);
    L += v.y * wgt;
    float4 o4 = *(const float4*)(ops[s] + e);
    acc.x += o4.x * wgt; acc.y += o4.y * wgt;
    acc.z += o4.z * wgt; acc.w += o4.w * wgt;
  }
  float inv = 1.0f / L;
  *(float4*)(ao + e) = make_float4(acc.x * inv, acc.y * inv, acc.z * inv, acc.w * inv);
}

// ---------------- K4: out projection [4096,512]x[512,512] + bias ----------------
__global__ __launch_bounds__(256) void k_gemm_out(const float* __restrict__ a,
    const float* __restrict__ w, const float* __restrict__ bias,
    float* __restrict__ out) {
  __shared__ float As[16][68];
  __shared__ float Bs[16][68];
  const int t = threadIdx.x;
  const int colBase = blockIdx.x * 64;
  const int rowBase = blockIdx.y * 64;
  const int ti = t >> 4, tj = t & 15;
  const int ar = t >> 2, ak = (t & 3) * 4;
  const int bk = t >> 4, bc = (t & 15) * 4;
  float acc[4][4] = {};
  for (int kt = 0; kt < 512; kt += 16) {
    float4 av = *(const float4*)(a + (size_t)(rowBase + ar) * 512 + kt + ak);
    float4 wv = *(const float4*)(w + (size_t)(kt + bk) * 512 + colBase + bc);
    As[ak + 0][ar] = av.x;
    As[ak + 1][ar] = av.y;
    As[ak + 2][ar] = av.z;
    As[ak + 3][ar] = av.w;
    *(float4*)&Bs[bk][bc] = wv;
    __syncthreads();
#pragma unroll
    for (int kk = 0; kk < 16; ++kk) {
      float4 a4 = *(const float4*)&As[kk][ti * 4];
      float4 b4 = *(const float4*)&Bs[kk][tj * 4];
      float aa[4] = {a4.x, a4.y, a4.z, a4.w};
      float bb2[4] = {b4.x, b4.y, b4.z, b4.w};
#pragma unroll
      for (int r = 0; r < 4; ++r)
#pragma unroll
        for (int c = 0; c < 4; ++c)
          acc[r][c] += aa[r] * bb2[c];
    }
    __syncthreads();
  }
  float4 bias4 = *(const float4*)(bias + colBase + tj * 4);
#pragma unroll
  for (int r = 0; r < 4; ++r) {
    int row = rowBase + ti * 4 + r;
    float4 vv = make_float4(acc[r][0] + bias4.x, acc[r][1] + bias4.y,
                            acc[r][2] + bias4.z, acc[r][3] + bias4.w);
    *(float4*)(out + (size_t)row * 512 + colBase + tj * 4) = vv;
  }
}

extern "C" void kernel_launch(void* const* d_in, const int* in_sizes, int n_in,
                              void* d_out, int out_size, void* d_ws, size_t ws_size,
                              hipStream_t stream) {
  (void)in_sizes; (void)n_in; (void)out_size;
  const float* x    = (const float*)d_in[0];
  const float* sph  = (const float*)d_in[1];
  const float* g    = (const float*)d_in[2];
  const float* bta  = (const float*)d_in[3];
  const float* wqkv = (const float*)d_in[4];
  const float* wout = (const float*)d_in[5];
  const float* bout = (const float*)d_in[6];
  float* out = (float*)d_out;
  char* ws = (char*)d_ws;

  unsigned short* qhi  = (unsigned short*)(ws + OFF_QHI);
  unsigned short* qlo  = (unsigned short*)(ws + OFF_QLO);
  unsigned short* khi  = (unsigned short*)(ws + OFF_KHI);
  unsigned short* klo  = (unsigned short*)(ws + OFF_KLO);
  unsigned short* vthi = (unsigned short*)(ws + OFF_VTHI);
  unsigned short* vtlo = (unsigned short*)(ws + OFF_VTLO);
  unsigned short* vnhi = (unsigned short*)(ws + OFF_VNHI);
  unsigned short* vnlo = (unsigned short*)(ws + OFF_VNLO);
  float2* ml = (float2*)(ws + OFF_ML);
  float* mu = (float*)(ws + OFF_MU);
  float* rs = (float*)(ws + OFF_RS);

  // runtime split selection by ws_size (deterministic: ws_size is constant)
  int S;
  if      (ws_size >= (73u << 20)) S = 4;
  else if (ws_size >= (55u << 20)) S = 2;
  else                             S = 1;
  float* ao = (float*)(ws + ((ws_size >= (46u << 20)) ? OFF_AO_BIG : OFF_AO_SMALL));
  float* op0 = ao;
  float* op1 = (S > 1) ? (float*)(ws + OFF_OP1) : ao;
  float* op2 = (S > 2) ? (float*)(ws + OFF_OP1 + (9u << 20)) : ao;
  float* op3 = (S > 3) ? (float*)(ws + OFF_OP1 + (18u << 20)) : ao;
  const int jLen = kN / S;

  k_ln_stats<<<dim3(1024), dim3(256), 0, stream>>>(x, mu, rs);
  k_gemm_qkv<<<dim3(24, 64), dim3(256), 0, stream>>>(x, mu, rs, g, bta, wqkv,
                                                     qhi, qlo, khi, klo, vnhi, vnlo);
  k_vtrans<<<dim3(1024), dim3(256), 0, stream>>>(vnhi, vnlo, vthi, vtlo);
  k_attn<<<dim3(256 * S), dim3(512), 0, stream>>>(qhi, qlo, khi, klo, vthi, vtlo,
                                                  sph, op0, op1, op2, op3, ml, jLen);
  k_combine<<<dim3(2048), dim3(256), 0, stream>>>(op0, op1, op2, op3, ml, S, ao);
  k_gemm_out<<<dim3(8, 64), dim3(256), 0, stream>>>(ao, wout, bout, out);
}

// Round 4
// 380.018 us; speedup vs baseline: 1.1168x; 1.1168x over previous
//
#include <hip/hip_runtime.h>
#include <math.h>

// GlobalSphereAttention: LN -> QKV -> per-head dots * scale * (1+sph)
//   -> cross-head mean/std(ddof=1) normalize -> softmax(j) -> PV -> out proj.
// B=2, N=2048, DIM=512, HEADS=8, DHEAD=64.
// Round 4: spill-free attention. 256-thr blocks (4 waves, 2 heads/wave),
// j-tile=32, 2 barriers/tile, register budget ~145 (launch_bounds(256,3)).

typedef __attribute__((ext_vector_type(8))) short bf16x8;
typedef __attribute__((ext_vector_type(8))) unsigned short u16x8;
typedef __attribute__((ext_vector_type(4))) float f32x4;

constexpr int kDim = 512;
constexpr int kN = 2048;
constexpr float kEps = 1e-5f;
constexpr float kScale = 0.125f; // 64^-0.5

// ws layout (byte offsets)
constexpr size_t OFF_QHI  = 0;
constexpr size_t OFF_QLO  = 4u << 20;
constexpr size_t OFF_KHI  = 8u << 20;
constexpr size_t OFF_KLO  = 12u << 20;
constexpr size_t OFF_VTHI = 16u << 20;  // transposed [bh][d][n]
constexpr size_t OFF_VTLO = 20u << 20;
constexpr size_t OFF_VNHI = 24u << 20;  // natural [bh][n][d] (dead after vtrans)
constexpr size_t OFF_VNLO = 28u << 20;
constexpr size_t OFF_ML   = 33u << 20;  // float2 [s][bh16][n]  (<=2MB)
constexpr size_t OFF_MU   = 35u << 20;
constexpr size_t OFF_RS   = (35u << 20) + (64u << 10);
constexpr size_t OFF_AO_BIG   = 36u << 20;  // 8.4MB
constexpr size_t OFF_AO_SMALL = 24u << 20;  // aliases VN planes (dead by then)
constexpr size_t OFF_OP1  = 45u << 20;      // + (s-1)*9MB for s=1..3

__device__ __forceinline__ unsigned short bf16_rne(float f) {
  unsigned int u = __float_as_uint(f);
  u += 0x7fffu + ((u >> 16) & 1u);
  return (unsigned short)(u >> 16);
}
__device__ __forceinline__ float bf16f(unsigned short h) {
  return __uint_as_float(((unsigned int)h) << 16);
}
__device__ __forceinline__ f32x4 mfma16(bf16x8 a, bf16x8 b, f32x4 c) {
  return __builtin_amdgcn_mfma_f32_16x16x32_bf16(a, b, c, 0, 0, 0);
}

// ---------------- K1: LayerNorm row stats ----------------
__global__ __launch_bounds__(256) void k_ln_stats(const float* __restrict__ x,
                                                  float* __restrict__ mu,
                                                  float* __restrict__ rs) {
  int row = blockIdx.x * 4 + (threadIdx.x >> 6);
  int lane = threadIdx.x & 63;
  const float4* xr = (const float4*)(x + (size_t)row * kDim + lane * 8);
  float4 a = xr[0], b = xr[1];
  float s = a.x + a.y + a.z + a.w + b.x + b.y + b.z + b.w;
  float q = a.x*a.x + a.y*a.y + a.z*a.z + a.w*a.w
          + b.x*b.x + b.y*b.y + b.z*b.z + b.w*b.w;
#pragma unroll
  for (int off = 32; off > 0; off >>= 1) {
    s += __shfl_down(s, off);
    q += __shfl_down(q, off);
  }
  if (lane == 0) {
    float m = s * (1.0f / kDim);
    float v = q * (1.0f / kDim) - m * m;
    mu[row] = m;
    rs[row] = 1.0f / sqrtf(v + kEps);
  }
}

// ---------------- K2: fused-LN QKV GEMM, epilogue -> bf16 hi/lo planes ------
__global__ __launch_bounds__(256) void k_gemm_qkv(const float* __restrict__ x,
    const float* __restrict__ mu, const float* __restrict__ rs,
    const float* __restrict__ g, const float* __restrict__ bta,
    const float* __restrict__ w,
    unsigned short* __restrict__ qhi, unsigned short* __restrict__ qlo,
    unsigned short* __restrict__ khi, unsigned short* __restrict__ klo,
    unsigned short* __restrict__ vnhi, unsigned short* __restrict__ vnlo) {
  __shared__ float As[16][68];  // A^T tile (k-major)
  __shared__ float Bs[16][68];
  const int t = threadIdx.x;
  const int colBase = blockIdx.x * 64;
  const int rowBase = blockIdx.y * 64;
  const int ti = t >> 4, tj = t & 15;
  const int ar = t >> 2, ak = (t & 3) * 4;
  const int bk = t >> 4, bc = (t & 15) * 4;
  const int arow = rowBase + ar;
  const float amu = mu[arow], ars = rs[arow];
  float acc[4][4] = {};
  for (int kt = 0; kt < kDim; kt += 16) {
    float4 av = *(const float4*)(x + (size_t)arow * kDim + kt + ak);
    float4 gv = *(const float4*)(g + kt + ak);
    float4 bv = *(const float4*)(bta + kt + ak);
    float4 wv = *(const float4*)(w + (size_t)(kt + bk) * 1536 + colBase + bc);
    As[ak + 0][ar] = (av.x - amu) * ars * gv.x + bv.x;
    As[ak + 1][ar] = (av.y - amu) * ars * gv.y + bv.y;
    As[ak + 2][ar] = (av.z - amu) * ars * gv.z + bv.z;
    As[ak + 3][ar] = (av.w - amu) * ars * gv.w + bv.w;
    *(float4*)&Bs[bk][bc] = wv;
    __syncthreads();
#pragma unroll
    for (int kk = 0; kk < 16; ++kk) {
      float4 a4 = *(const float4*)&As[kk][ti * 4];
      float4 b4 = *(const float4*)&Bs[kk][tj * 4];
      float aa[4] = {a4.x, a4.y, a4.z, a4.w};
      float bb2[4] = {b4.x, b4.y, b4.z, b4.w};
#pragma unroll
      for (int r = 0; r < 4; ++r)
#pragma unroll
        for (int c = 0; c < 4; ++c)
          acc[r][c] += aa[r] * bb2[c];
    }
    __syncthreads();
  }
  const int col0 = colBase + tj * 4;
  const int which = col0 >> 9;
  const int cc = col0 & 511;
  const int h = cc >> 6, d = cc & 63;
  unsigned short* ph = (which == 0) ? qhi : ((which == 1) ? khi : vnhi);
  unsigned short* pl = (which == 0) ? qlo : ((which == 1) ? klo : vnlo);
#pragma unroll
  for (int r = 0; r < 4; ++r) {
    int row = rowBase + ti * 4 + r;
    int bI = row >> 11, n = row & 2047;
    size_t base = ((size_t)(bI * 8 + h) * kN + n) * 64 + d;
    unsigned short hv[4], lv[4];
#pragma unroll
    for (int c = 0; c < 4; ++c) {
      hv[c] = bf16_rne(acc[r][c]);
      lv[c] = bf16_rne(acc[r][c] - bf16f(hv[c]));
    }
    *(ushort4*)(ph + base) = make_ushort4(hv[0], hv[1], hv[2], hv[3]);
    *(ushort4*)(pl + base) = make_ushort4(lv[0], lv[1], lv[2], lv[3]);
  }
}

// ---------------- K2b: V transpose [bh][n][64] -> [bh][d][n] ----------------
__global__ __launch_bounds__(256) void k_vtrans(
    const unsigned short* __restrict__ vnhi, const unsigned short* __restrict__ vnlo,
    unsigned short* __restrict__ vthi, unsigned short* __restrict__ vtlo) {
  __shared__ unsigned short tile[64][72];  // 72: row stride 144B (16B-mult)
  const int id = blockIdx.x;
  const int p = id >> 9;
  const int bh = (id >> 5) & 15;
  const int nt = id & 31;
  const unsigned short* src = (p ? vnlo : vnhi) + ((size_t)bh * kN + nt * 64) * 64;
  unsigned short* dst = (p ? vtlo : vthi) + (size_t)bh * 64 * kN + nt * 64;
  const int r = threadIdx.x >> 3;
  const int c = (threadIdx.x & 7) * 8;
#pragma unroll
  for (int rr = 0; rr < 64; rr += 32) {
    u16x8 v = *(const u16x8*)(src + (size_t)(r + rr) * 64 + c);
    *(u16x8*)&tile[r + rr][c] = v;
  }
  __syncthreads();
#pragma unroll
  for (int dd = 0; dd < 64; dd += 32) {
    int d = r + dd;
    u16x8 v;
#pragma unroll
    for (int e = 0; e < 8; ++e) v[e] = tile[c + e][d];
    *(u16x8*)(dst + (size_t)d * kN + c) = v;
  }
}

// ---------------- K3: fused sphere attention (spill-free) ----------------
// grid = S * 256 blocks x 256 threads (4 waves; wave w owns heads 2w, 2w+1).
// Per block: 16 q-rows, j-loop in 32-tiles over [jStart, jEnd).
__global__ __launch_bounds__(256, 3) void k_attn(
    const unsigned short* __restrict__ qhi, const unsigned short* __restrict__ qlo,
    const unsigned short* __restrict__ khi, const unsigned short* __restrict__ klo,
    const unsigned short* __restrict__ vthi, const unsigned short* __restrict__ vtlo,
    const float* __restrict__ sph,
    float* __restrict__ op0, float* __restrict__ op1,
    float* __restrict__ op2, float* __restrict__ op3,
    float2* __restrict__ ml, int jLen) {
  constexpr int SSTR = 36;           // dwords/row, 144B (16B-aligned, 2-way banks)
  __shared__ float Ss[128 * SSTR];   // 18.4 KB; row = h*16+i; also packed P (u32)
  __shared__ float Fbuf[8][16];

  const int t = threadIdx.x;
  const int w = t >> 6;
  const int lane = t & 63;
  const int col = lane & 15;
  const int g = lane >> 4;
  const int tileId = blockIdx.x & 255;
  const int sId = blockIdx.x >> 8;
  const int bI = tileId >> 7;
  const int i0 = (tileId & 127) << 4;
  const int jStart = sId * jLen;
  const int jEnd = jStart + jLen;
  float* opart = (sId == 0) ? op0 : ((sId == 1) ? op1 : ((sId == 2) ? op2 : op3));

  // ---- persistent Q fragments for the wave's two heads (32 VGPRs) ----
  bf16x8 qh[2][2], ql[2][2];
#pragma unroll
  for (int hp = 0; hp < 2; ++hp) {
    const size_t bh = (size_t)bI * 8 + 2 * w + hp;
    const size_t qoff = (bh * kN + i0 + col) * 64 + g * 8;
    qh[hp][0] = *(const bf16x8*)(qhi + qoff);
    qh[hp][1] = *(const bf16x8*)(qhi + qoff + 32);
    ql[hp][0] = *(const bf16x8*)(qlo + qoff);
    ql[hp][1] = *(const bf16x8*)(qlo + qoff + 32);
  }

  f32x4 oacc[2][4];
#pragma unroll
  for (int hp = 0; hp < 2; ++hp)
#pragma unroll
    for (int nf = 0; nf < 4; ++nf) oacc[hp][nf] = (f32x4){0.f, 0.f, 0.f, 0.f};

  // C-phase (softmax) ownership: lane -> (head-pair, row, j-half)
  const int hpC = lane >> 5;
  const int iC = (lane >> 1) & 15;
  const int jh = lane & 1;
  const int rowC = (2 * w + hpC) * 16 + iC;
  float mreg = -INFINITY, lreg = 0.f;

  // B-phase (cross-head norm) ownership: thread -> (row i, j-pair)
  const int iB = t >> 4;
  const int j2 = (t & 15) * 2;

  unsigned int* sb32 = (unsigned int*)Ss;

  for (int j0 = jStart; j0 < jEnd; j0 += 32) {
    // ---- A: QK^T per head (transient K frags: 32 regs) ----
#pragma unroll
    for (int hp = 0; hp < 2; ++hp) {
      const int h = 2 * w + hp;
      const size_t bh = (size_t)bI * 8 + h;
      const unsigned short* kb_h = khi + (bh * kN + j0 + col) * 64 + g * 8;
      const unsigned short* kb_l = klo + (bh * kN + j0 + col) * 64 + g * 8;
      bf16x8 kh00 = *(const bf16x8*)(kb_h);
      bf16x8 kh01 = *(const bf16x8*)(kb_h + 32);
      bf16x8 kh10 = *(const bf16x8*)(kb_h + 16 * 64);
      bf16x8 kh11 = *(const bf16x8*)(kb_h + 16 * 64 + 32);
      bf16x8 kl00 = *(const bf16x8*)(kb_l);
      bf16x8 kl01 = *(const bf16x8*)(kb_l + 32);
      bf16x8 kl10 = *(const bf16x8*)(kb_l + 16 * 64);
      bf16x8 kl11 = *(const bf16x8*)(kb_l + 16 * 64 + 32);
      f32x4 s0 = (f32x4){0.f, 0.f, 0.f, 0.f};
      s0 = mfma16(qh[hp][0], kh00, s0);
      s0 = mfma16(qh[hp][1], kh01, s0);
      s0 = mfma16(ql[hp][0], kh00, s0);
      s0 = mfma16(ql[hp][1], kh01, s0);
      s0 = mfma16(qh[hp][0], kl00, s0);
      s0 = mfma16(qh[hp][1], kl01, s0);
      f32x4 s1 = (f32x4){0.f, 0.f, 0.f, 0.f};
      s1 = mfma16(qh[hp][0], kh10, s1);
      s1 = mfma16(qh[hp][1], kh11, s1);
      s1 = mfma16(ql[hp][0], kh10, s1);
      s1 = mfma16(ql[hp][1], kh11, s1);
      s1 = mfma16(qh[hp][0], kl10, s1);
      s1 = mfma16(qh[hp][1], kl11, s1);
      // C/D: col=lane&15 (j), row=g*4+r (i)
#pragma unroll
      for (int r = 0; r < 4; ++r) {
        Ss[(h * 16 + g * 4 + r) * SSTR + col] = s0[r];
        Ss[(h * 16 + g * 4 + r) * SSTR + 16 + col] = s1[r];
      }
    }
    // ---- issue sph + V-hi loads early (land during B/C) ----
    float2 sphv = *(const float2*)(sph + (size_t)(i0 + iB) * kN + j0 + j2);
    bf16x8 vhf[2][4];
#pragma unroll
    for (int hp = 0; hp < 2; ++hp) {
      const size_t bh = (size_t)bI * 8 + 2 * w + hp;
      const unsigned short* vb = vthi + (bh * 64 + col) * kN + j0 + g * 8;
#pragma unroll
      for (int nf = 0; nf < 4; ++nf)
        vhf[hp][nf] = *(const bf16x8*)(vb + (size_t)(nf * 16) * kN);
    }
    __syncthreads();
    // ---- B: cross-head normalization (2 (i,j) per thread, float2) ----
    {
      const float ma = kScale * (1.0f + sphv.x);
      const float mb = kScale * (1.0f + sphv.y);
      float da[8], db[8];
      float sa = 0.f, sb2 = 0.f;
#pragma unroll
      for (int hh = 0; hh < 8; ++hh) {
        float2 v = *(const float2*)&Ss[(hh * 16 + iB) * SSTR + j2];
        da[hh] = v.x * ma; sa += da[hh];
        db[hh] = v.y * mb; sb2 += db[hh];
      }
      const float mea = sa * 0.125f, meb = sb2 * 0.125f;
      float va = 0.f, vb2 = 0.f;
#pragma unroll
      for (int hh = 0; hh < 8; ++hh) {
        float xa = da[hh] - mea; va += xa * xa;
        float xb = db[hh] - meb; vb2 += xb * xb;
      }
      const float ia = rsqrtf(va * (1.0f / 7.0f));
      const float ib2 = rsqrtf(vb2 * (1.0f / 7.0f));
#pragma unroll
      for (int hh = 0; hh < 8; ++hh) {
        float2 o2 = make_float2((da[hh] - mea) * ia, (db[hh] - meb) * ib2);
        *(float2*)&Ss[(hh * 16 + iB) * SSTR + j2] = o2;
      }
    }
    __syncthreads();
    // ---- C: online softmax, wave-local rows; pack P in place ----
    {
      const float* srow = &Ss[rowC * SSTR + jh * 16];
      float vals[16];
#pragma unroll
      for (int q = 0; q < 4; ++q) {
        float4 dv = *(const float4*)(srow + q * 4);
        vals[q * 4 + 0] = dv.x; vals[q * 4 + 1] = dv.y;
        vals[q * 4 + 2] = dv.z; vals[q * 4 + 3] = dv.w;
      }
      float mx = vals[0];
#pragma unroll
      for (int q = 1; q < 16; ++q) mx = fmaxf(mx, vals[q]);
      mx = fmaxf(mx, __shfl_xor(mx, 1));
      const float Mn = fmaxf(mreg, mx);
      const float f = __expf(mreg - Mn);
      float s = 0.f;
      float pv[16];
#pragma unroll
      for (int q = 0; q < 16; ++q) {
        pv[q] = __expf(vals[q] - Mn);
        s += pv[q];
      }
      s += __shfl_xor(s, 1);
      lreg = lreg * f + s;
      mreg = Mn;
      if (jh == 0) Fbuf[2 * w + hpC][iC] = f;
      unsigned int* prow = sb32 + rowC * SSTR + jh * 16;
#pragma unroll
      for (int q = 0; q < 4; ++q) {
        unsigned int pk[4];
#pragma unroll
        for (int e = 0; e < 4; ++e) {
          float p = pv[q * 4 + e];
          unsigned short hi2 = bf16_rne(p);
          unsigned short lo2 = bf16_rne(p - bf16f(hi2));
          pk[e] = (unsigned int)hi2 | ((unsigned int)lo2 << 16);
        }
        *(uint4*)(prow + q * 4) = make_uint4(pk[0], pk[1], pk[2], pk[3]);
      }
    }
    // ---- D: PV per head (wave-local; no barrier needed) ----
#pragma unroll
    for (int hp = 0; hp < 2; ++hp) {
      const int h = 2 * w + hp;
      const size_t bh = (size_t)bI * 8 + h;
      // P A-frag: row=lane&15, k=g*8+e -> 8 consecutive u32
      const unsigned int* pb = (const unsigned int*)sb32 + (h * 16 + col) * SSTR + g * 8;
      uint4 u0 = *(const uint4*)(pb);
      uint4 u1 = *(const uint4*)(pb + 4);
      unsigned int uu[8] = {u0.x, u0.y, u0.z, u0.w, u1.x, u1.y, u1.z, u1.w};
      bf16x8 ph8, pl8;
#pragma unroll
      for (int e = 0; e < 8; ++e) {
        ph8[e] = (short)(uu[e] & 0xffffu);
        pl8[e] = (short)(uu[e] >> 16);
      }
      const unsigned short* vbl = vtlo + (bh * 64 + col) * kN + j0 + g * 8;
      float fr[4];
#pragma unroll
      for (int r = 0; r < 4; ++r) fr[r] = Fbuf[h][g * 4 + r];
#pragma unroll
      for (int nf = 0; nf < 4; ++nf) {
        bf16x8 vlf = *(const bf16x8*)(vbl + (size_t)(nf * 16) * kN);
        f32x4 a = oacc[hp][nf];
#pragma unroll
        for (int r = 0; r < 4; ++r) a[r] *= fr[r];
        a = mfma16(ph8, vhf[hp][nf], a);
        a = mfma16(pl8, vhf[hp][nf], a);
        a = mfma16(ph8, vlf, a);
        oacc[hp][nf] = a;
      }
    }
  }
  // ---- epilogue: (m,l) from C-ownership; unnormalized O from D-ownership ----
  if (jh == 0)
    ml[((size_t)sId * 16 + bI * 8 + 2 * w + hpC) * kN + (i0 + iC)] =
        make_float2(mreg, lreg);
#pragma unroll
  for (int hp = 0; hp < 2; ++hp) {
    const int h = 2 * w + hp;
#pragma unroll
    for (int r = 0; r < 4; ++r) {
      float* dst = opart + ((size_t)bI * kN + i0 + g * 4 + r) * 512 + h * 64;
#pragma unroll
      for (int nf = 0; nf < 4; ++nf)
        dst[nf * 16 + col] = oacc[hp][nf][r];
    }
  }
}

// ---------------- K3b: combine split partials -> AO ----------------
__global__ __launch_bounds__(256) void k_combine(
    const float* __restrict__ op0, const float* __restrict__ op1,
    const float* __restrict__ op2, const float* __restrict__ op3,
    const float2* __restrict__ ml, int S, float* __restrict__ ao) {
  const size_t e = ((size_t)blockIdx.x * 256 + threadIdx.x) * 4;
  const int row = (int)(e >> 9);
  const int col = (int)(e & 511);
  const int h = col >> 6;
  const int bI = row >> 11;
  const int n = row & 2047;
  const size_t mlBase = (size_t)(bI * 8 + h) * kN + n;
  float m0 = ml[mlBase].x;
  float ms = m0;
  if (S > 1) ms = fmaxf(ms, ml[(size_t)16 * kN + mlBase].x);
  if (S > 2) {
    ms = fmaxf(ms, ml[(size_t)32 * kN + mlBase].x);
    ms = fmaxf(ms, ml[(size_t)48 * kN + mlBase].x);
  }
  const float* ops[4] = {op0, op1, op2, op3};
  float L = 0.f;
  float4 acc = make_float4(0.f, 0.f, 0.f, 0.f);
  for (int s = 0; s < S; ++s) {
    float2 v = ml[(size_t)s * 16 * kN + mlBase];
    float wgt = __expf(v.x - ms);
    L += v.y * wgt;
    float4 o4 = *(const float4*)(ops[s] + e);
    acc.x += o4.x * wgt; acc.y += o4.y * wgt;
    acc.z += o4.z * wgt; acc.w += o4.w * wgt;
  }
  float inv = 1.0f / L;
  *(float4*)(ao + e) = make_float4(acc.x * inv, acc.y * inv, acc.z * inv, acc.w * inv);
}

// ---------------- K4: out projection [4096,512]x[512,512] + bias ----------------
__global__ __launch_bounds__(256) void k_gemm_out(const float* __restrict__ a,
    const float* __restrict__ w, const float* __restrict__ bias,
    float* __restrict__ out) {
  __shared__ float As[16][68];
  __shared__ float Bs[16][68];
  const int t = threadIdx.x;
  const int colBase = blockIdx.x * 64;
  const int rowBase = blockIdx.y * 64;
  const int ti = t >> 4, tj = t & 15;
  const int ar = t >> 2, ak = (t & 3) * 4;
  const int bk = t >> 4, bc = (t & 15) * 4;
  float acc[4][4] = {};
  for (int kt = 0; kt < 512; kt += 16) {
    float4 av = *(const float4*)(a + (size_t)(rowBase + ar) * 512 + kt + ak);
    float4 wv = *(const float4*)(w + (size_t)(kt + bk) * 512 + colBase + bc);
    As[ak + 0][ar] = av.x;
    As[ak + 1][ar] = av.y;
    As[ak + 2][ar] = av.z;
    As[ak + 3][ar] = av.w;
    *(float4*)&Bs[bk][bc] = wv;
    __syncthreads();
#pragma unroll
    for (int kk = 0; kk < 16; ++kk) {
      float4 a4 = *(const float4*)&As[kk][ti * 4];
      float4 b4 = *(const float4*)&Bs[kk][tj * 4];
      float aa[4] = {a4.x, a4.y, a4.z, a4.w};
      float bb2[4] = {b4.x, b4.y, b4.z, b4.w};
#pragma unroll
      for (int r = 0; r < 4; ++r)
#pragma unroll
        for (int c = 0; c < 4; ++c)
          acc[r][c] += aa[r] * bb2[c];
    }
    __syncthreads();
  }
  float4 bias4 = *(const float4*)(bias + colBase + tj * 4);
#pragma unroll
  for (int r = 0; r < 4; ++r) {
    int row = rowBase + ti * 4 + r;
    float4 vv = make_float4(acc[r][0] + bias4.x, acc[r][1] + bias4.y,
                            acc[r][2] + bias4.z, acc[r][3] + bias4.w);
    *(float4*)(out + (size_t)row * 512 + colBase + tj * 4) = vv;
  }
}

extern "C" void kernel_launch(void* const* d_in, const int* in_sizes, int n_in,
                              void* d_out, int out_size, void* d_ws, size_t ws_size,
                              hipStream_t stream) {
  (void)in_sizes; (void)n_in; (void)out_size;
  const float* x    = (const float*)d_in[0];
  const float* sph  = (const float*)d_in[1];
  const float* g    = (const float*)d_in[2];
  const float* bta  = (const float*)d_in[3];
  const float* wqkv = (const float*)d_in[4];
  const float* wout = (const float*)d_in[5];
  const float* bout = (const float*)d_in[6];
  float* out = (float*)d_out;
  char* ws = (char*)d_ws;

  unsigned short* qhi  = (unsigned short*)(ws + OFF_QHI);
  unsigned short* qlo  = (unsigned short*)(ws + OFF_QLO);
  unsigned short* khi  = (unsigned short*)(ws + OFF_KHI);
  unsigned short* klo  = (unsigned short*)(ws + OFF_KLO);
  unsigned short* vthi = (unsigned short*)(ws + OFF_VTHI);
  unsigned short* vtlo = (unsigned short*)(ws + OFF_VTLO);
  unsigned short* vnhi = (unsigned short*)(ws + OFF_VNHI);
  unsigned short* vnlo = (unsigned short*)(ws + OFF_VNLO);
  float2* ml = (float2*)(ws + OFF_ML);
  float* mu = (float*)(ws + OFF_MU);
  float* rs = (float*)(ws + OFF_RS);

  // runtime split selection by ws_size (deterministic: ws_size is constant)
  int S;
  if      (ws_size >= (73u << 20)) S = 4;
  else if (ws_size >= (55u << 20)) S = 2;
  else                             S = 1;
  float* ao = (float*)(ws + ((ws_size >= (46u << 20)) ? OFF_AO_BIG : OFF_AO_SMALL));
  float* op0 = ao;
  float* op1 = (S > 1) ? (float*)(ws + OFF_OP1) : ao;
  float* op2 = (S > 2) ? (float*)(ws + OFF_OP1 + (9u << 20)) : ao;
  float* op3 = (S > 3) ? (float*)(ws + OFF_OP1 + (18u << 20)) : ao;
  const int jLen = kN / S;

  k_ln_stats<<<dim3(1024), dim3(256), 0, stream>>>(x, mu, rs);
  k_gemm_qkv<<<dim3(24, 64), dim3(256), 0, stream>>>(x, mu, rs, g, bta, wqkv,
                                                     qhi, qlo, khi, klo, vnhi, vnlo);
  k_vtrans<<<dim3(1024), dim3(256), 0, stream>>>(vnhi, vnlo, vthi, vtlo);
  k_attn<<<dim3(256 * S), dim3(256), 0, stream>>>(qhi, qlo, khi, klo, vthi, vtlo,
                                                  sph, op0, op1, op2, op3, ml, jLen);
  k_combine<<<dim3(2048), dim3(256), 0, stream>>>(op0, op1, op2, op3, ml, S, ao);
  k_gemm_out<<<dim3(8, 64), dim3(256), 0, stream>>>(ao, wout, bout, out);
}

// Round 5
// 378.829 us; speedup vs baseline: 1.1203x; 1.0031x over previous
//
#include <hip/hip_runtime.h>
#include <math.h>

// GlobalSphereAttention: LN -> QKV -> per-head dots * scale * (1+sph)
//   -> cross-head mean/std(ddof=1) normalize -> softmax(j) -> PV -> out proj.
// B=2, N=2048, DIM=512, HEADS=8, DHEAD=64.
// Round 5: latency-lean attention. 512-thr blocks (8 waves, wave=head),
// j-tile 32, P kept in registers (softmax ownership == PV A-frag mapping),
// sph prefetch, V issued under softmax, launch_bounds(512,4).

typedef __attribute__((ext_vector_type(8))) short bf16x8;
typedef __attribute__((ext_vector_type(8))) unsigned short u16x8;
typedef __attribute__((ext_vector_type(4))) float f32x4;

constexpr int kDim = 512;
constexpr int kN = 2048;
constexpr float kEps = 1e-5f;
constexpr float kScale = 0.125f; // 64^-0.5

// ws layout (byte offsets)
constexpr size_t OFF_QHI  = 0;
constexpr size_t OFF_QLO  = 4u << 20;
constexpr size_t OFF_KHI  = 8u << 20;
constexpr size_t OFF_KLO  = 12u << 20;
constexpr size_t OFF_VTHI = 16u << 20;  // transposed [bh][d][n]
constexpr size_t OFF_VTLO = 20u << 20;
constexpr size_t OFF_VNHI = 24u << 20;  // natural [bh][n][d] (dead after vtrans)
constexpr size_t OFF_VNLO = 28u << 20;
constexpr size_t OFF_ML   = 33u << 20;  // float2 [s][bh16][n]  (<=2MB)
constexpr size_t OFF_MU   = 35u << 20;
constexpr size_t OFF_RS   = (35u << 20) + (64u << 10);
constexpr size_t OFF_AO_BIG   = 36u << 20;  // 8.4MB
constexpr size_t OFF_AO_SMALL = 24u << 20;  // aliases VN planes (dead by then)
constexpr size_t OFF_OP1  = 45u << 20;      // + (s-1)*9MB for s=1..3

// split x into bf16 hi (trunc) + bf16 lo (trunc of exact remainder):
// |x - hi - lo| <= 2^-16 |x|
__device__ __forceinline__ void bf16_split(float x, unsigned short& hi,
                                           unsigned short& lo) {
  unsigned int u = __float_as_uint(x);
  hi = (unsigned short)(u >> 16);
  float r = x - __uint_as_float(u & 0xffff0000u);  // exact
  lo = (unsigned short)(__float_as_uint(r) >> 16);
}
__device__ __forceinline__ f32x4 mfma16(bf16x8 a, bf16x8 b, f32x4 c) {
  return __builtin_amdgcn_mfma_f32_16x16x32_bf16(a, b, c, 0, 0, 0);
}

// ---------------- K1: LayerNorm row stats ----------------
__global__ __launch_bounds__(256) void k_ln_stats(const float* __restrict__ x,
                                                  float* __restrict__ mu,
                                                  float* __restrict__ rs) {
  int row = blockIdx.x * 4 + (threadIdx.x >> 6);
  int lane = threadIdx.x & 63;
  const float4* xr = (const float4*)(x + (size_t)row * kDim + lane * 8);
  float4 a = xr[0], b = xr[1];
  float s = a.x + a.y + a.z + a.w + b.x + b.y + b.z + b.w;
  float q = a.x*a.x + a.y*a.y + a.z*a.z + a.w*a.w
          + b.x*b.x + b.y*b.y + b.z*b.z + b.w*b.w;
#pragma unroll
  for (int off = 32; off > 0; off >>= 1) {
    s += __shfl_down(s, off);
    q += __shfl_down(q, off);
  }
  if (lane == 0) {
    float m = s * (1.0f / kDim);
    float v = q * (1.0f / kDim) - m * m;
    mu[row] = m;
    rs[row] = 1.0f / sqrtf(v + kEps);
  }
}

// ---------------- K2: fused-LN QKV GEMM, epilogue -> bf16 hi/lo planes ------
__global__ __launch_bounds__(256) void k_gemm_qkv(const float* __restrict__ x,
    const float* __restrict__ mu, const float* __restrict__ rs,
    const float* __restrict__ g, const float* __restrict__ bta,
    const float* __restrict__ w,
    unsigned short* __restrict__ qhi, unsigned short* __restrict__ qlo,
    unsigned short* __restrict__ khi, unsigned short* __restrict__ klo,
    unsigned short* __restrict__ vnhi, unsigned short* __restrict__ vnlo) {
  __shared__ float As[16][68];  // A^T tile (k-major)
  __shared__ float Bs[16][68];
  const int t = threadIdx.x;
  const int colBase = blockIdx.x * 64;
  const int rowBase = blockIdx.y * 64;
  const int ti = t >> 4, tj = t & 15;
  const int ar = t >> 2, ak = (t & 3) * 4;
  const int bk = t >> 4, bc = (t & 15) * 4;
  const int arow = rowBase + ar;
  const float amu = mu[arow], ars = rs[arow];
  float acc[4][4] = {};
  for (int kt = 0; kt < kDim; kt += 16) {
    float4 av = *(const float4*)(x + (size_t)arow * kDim + kt + ak);
    float4 gv = *(const float4*)(g + kt + ak);
    float4 bv = *(const float4*)(bta + kt + ak);
    float4 wv = *(const float4*)(w + (size_t)(kt + bk) * 1536 + colBase + bc);
    As[ak + 0][ar] = (av.x - amu) * ars * gv.x + bv.x;
    As[ak + 1][ar] = (av.y - amu) * ars * gv.y + bv.y;
    As[ak + 2][ar] = (av.z - amu) * ars * gv.z + bv.z;
    As[ak + 3][ar] = (av.w - amu) * ars * gv.w + bv.w;
    *(float4*)&Bs[bk][bc] = wv;
    __syncthreads();
#pragma unroll
    for (int kk = 0; kk < 16; ++kk) {
      float4 a4 = *(const float4*)&As[kk][ti * 4];
      float4 b4 = *(const float4*)&Bs[kk][tj * 4];
      float aa[4] = {a4.x, a4.y, a4.z, a4.w};
      float bb2[4] = {b4.x, b4.y, b4.z, b4.w};
#pragma unroll
      for (int r = 0; r < 4; ++r)
#pragma unroll
        for (int c = 0; c < 4; ++c)
          acc[r][c] += aa[r] * bb2[c];
    }
    __syncthreads();
  }
  const int col0 = colBase + tj * 4;
  const int which = col0 >> 9;
  const int cc = col0 & 511;
  const int h = cc >> 6, d = cc & 63;
  unsigned short* ph = (which == 0) ? qhi : ((which == 1) ? khi : vnhi);
  unsigned short* pl = (which == 0) ? qlo : ((which == 1) ? klo : vnlo);
#pragma unroll
  for (int r = 0; r < 4; ++r) {
    int row = rowBase + ti * 4 + r;
    int bI = row >> 11, n = row & 2047;
    size_t base = ((size_t)(bI * 8 + h) * kN + n) * 64 + d;
    unsigned short hv[4], lv[4];
#pragma unroll
    for (int c = 0; c < 4; ++c) bf16_split(acc[r][c], hv[c], lv[c]);
    *(ushort4*)(ph + base) = make_ushort4(hv[0], hv[1], hv[2], hv[3]);
    *(ushort4*)(pl + base) = make_ushort4(lv[0], lv[1], lv[2], lv[3]);
  }
}

// ---------------- K2b: V transpose [bh][n][64] -> [bh][d][n] ----------------
__global__ __launch_bounds__(256) void k_vtrans(
    const unsigned short* __restrict__ vnhi, const unsigned short* __restrict__ vnlo,
    unsigned short* __restrict__ vthi, unsigned short* __restrict__ vtlo) {
  __shared__ unsigned short tile[64][72];  // 72: row stride 144B (16B-mult)
  const int id = blockIdx.x;
  const int p = id >> 9;
  const int bh = (id >> 5) & 15;
  const int nt = id & 31;
  const unsigned short* src = (p ? vnlo : vnhi) + ((size_t)bh * kN + nt * 64) * 64;
  unsigned short* dst = (p ? vtlo : vthi) + (size_t)bh * 64 * kN + nt * 64;
  const int r = threadIdx.x >> 3;
  const int c = (threadIdx.x & 7) * 8;
#pragma unroll
  for (int rr = 0; rr < 64; rr += 32) {
    u16x8 v = *(const u16x8*)(src + (size_t)(r + rr) * 64 + c);
    *(u16x8*)&tile[r + rr][c] = v;
  }
  __syncthreads();
#pragma unroll
  for (int dd = 0; dd < 64; dd += 32) {
    int d = r + dd;
    u16x8 v;
#pragma unroll
    for (int e = 0; e < 8; ++e) v[e] = tile[c + e][d];
    *(u16x8*)(dst + (size_t)d * kN + c) = v;
  }
}

// ---------------- K3: fused sphere attention ----------------
// grid = S*256 blocks x 512 threads (8 waves; wave = head). 16 q-rows/block.
__global__ __launch_bounds__(512, 4) void k_attn(
    const unsigned short* __restrict__ qhi, const unsigned short* __restrict__ qlo,
    const unsigned short* __restrict__ khi, const unsigned short* __restrict__ klo,
    const unsigned short* __restrict__ vthi, const unsigned short* __restrict__ vtlo,
    const float* __restrict__ sph,
    float* __restrict__ op0, float* __restrict__ op1,
    float* __restrict__ op2, float* __restrict__ op3,
    float2* __restrict__ ml, int jLen) {
  constexpr int SSTR = 36;           // dwords/row: 144B, 16B-aligned rows
  __shared__ float Ss[128 * SSTR];   // 18.4 KB scores

  const int t = threadIdx.x;
  const int h = t >> 6;
  const int lane = t & 63;
  const int col = lane & 15;
  const int g = lane >> 4;
  const int tileId = blockIdx.x & 255;
  const int sId = blockIdx.x >> 8;
  const int bI = tileId >> 7;
  const int i0 = (tileId & 127) << 4;
  const int jStart = sId * jLen;
  const int jEnd = jStart + jLen;
  const size_t bh = (size_t)bI * 8 + h;
  float* opart = (sId == 0) ? op0 : ((sId == 1) ? op1 : ((sId == 2) ? op2 : op3));

  // persistent Q fragments (A-frag: row=lane&15, k=d=g*8+e), hi/lo, d-chunks
  const size_t qoff = (bh * kN + i0 + col) * 64 + g * 8;
  const bf16x8 qh0 = *(const bf16x8*)(qhi + qoff);
  const bf16x8 qh1 = *(const bf16x8*)(qhi + qoff + 32);
  const bf16x8 ql0 = *(const bf16x8*)(qlo + qoff);
  const bf16x8 ql1 = *(const bf16x8*)(qlo + qoff + 32);

  const unsigned short* kb_h = khi + (bh * kN + col) * 64 + g * 8;
  const unsigned short* kb_l = klo + (bh * kN + col) * 64 + g * 8;
  const unsigned short* vb_h = vthi + (bh * 64 + col) * kN + g * 8;
  const unsigned short* vb_l = vtlo + (bh * 64 + col) * kN + g * 8;

  // norm-phase ownership: one (i,j) per thread
  const int iN = t >> 5;
  const int jN = t & 31;
  const float* sphp = sph + (size_t)(i0 + iN) * kN + jN;
  float sphcur = sphp[jStart];

  f32x4 oacc[4];
#pragma unroll
  for (int nf = 0; nf < 4; ++nf) oacc[nf] = (f32x4){0.f, 0.f, 0.f, 0.f};
  float mreg = -INFINITY, lreg = 0.f;

  for (int j0 = jStart; j0 < jEnd; j0 += 32) {
    // ---- A: QK^T (transient K frags; S = QhiKhi + QloKhi + QhiKlo) ----
    {
      const size_t ko = (size_t)j0 * 64;
      bf16x8 kh00 = *(const bf16x8*)(kb_h + ko);
      bf16x8 kh01 = *(const bf16x8*)(kb_h + ko + 32);
      bf16x8 kh10 = *(const bf16x8*)(kb_h + ko + 1024);
      bf16x8 kh11 = *(const bf16x8*)(kb_h + ko + 1056);
      bf16x8 kl00 = *(const bf16x8*)(kb_l + ko);
      bf16x8 kl01 = *(const bf16x8*)(kb_l + ko + 32);
      bf16x8 kl10 = *(const bf16x8*)(kb_l + ko + 1024);
      bf16x8 kl11 = *(const bf16x8*)(kb_l + ko + 1056);
      f32x4 s0 = (f32x4){0.f, 0.f, 0.f, 0.f};
      s0 = mfma16(qh0, kh00, s0);
      s0 = mfma16(qh1, kh01, s0);
      s0 = mfma16(ql0, kh00, s0);
      s0 = mfma16(ql1, kh01, s0);
      s0 = mfma16(qh0, kl00, s0);
      s0 = mfma16(qh1, kl01, s0);
      f32x4 s1 = (f32x4){0.f, 0.f, 0.f, 0.f};
      s1 = mfma16(qh0, kh10, s1);
      s1 = mfma16(qh1, kh11, s1);
      s1 = mfma16(ql0, kh10, s1);
      s1 = mfma16(ql1, kh11, s1);
      s1 = mfma16(qh0, kl10, s1);
      s1 = mfma16(qh1, kl11, s1);
      // C/D layout: col=lane&15 (j), row=g*4+r (i)
#pragma unroll
      for (int r = 0; r < 4; ++r) {
        Ss[(h * 16 + g * 4 + r) * SSTR + col] = s0[r];
        Ss[(h * 16 + g * 4 + r) * SSTR + 16 + col] = s1[r];
      }
    }
    // prefetch next tile's sph element (in flight across both barriers)
    const int jnn = (j0 + 32 < jEnd) ? (j0 + 32) : j0;
    const float sphnext = sphp[jnn];
    __syncthreads();
    // ---- B: cross-head normalization (1 (i,j) per thread) ----
    {
      const float mult = kScale * (1.0f + sphcur);
      float d8[8];
      float sum = 0.f;
#pragma unroll
      for (int hh = 0; hh < 8; ++hh) {
        d8[hh] = Ss[(hh * 16 + iN) * SSTR + jN] * mult;
        sum += d8[hh];
      }
      const float mean = sum * 0.125f;
      float var = 0.f;
#pragma unroll
      for (int hh = 0; hh < 8; ++hh) {
        float dd = d8[hh] - mean;
        var += dd * dd;
      }
      const float inv = rsqrtf(var * (1.0f / 7.0f));
#pragma unroll
      for (int hh = 0; hh < 8; ++hh)
        Ss[(hh * 16 + iN) * SSTR + jN] = (d8[hh] - mean) * inv;
    }
    sphcur = sphnext;
    __syncthreads();
    // ---- C: issue V loads, then softmax (lane owns row=col, j=g*8..g*8+7;
    //         identical to PV A-frag mapping -> P stays in registers) ----
    bf16x8 vhf[4], vlf[4];
#pragma unroll
    for (int nf = 0; nf < 4; ++nf) {
      vhf[nf] = *(const bf16x8*)(vb_h + (size_t)(nf * 16) * kN + j0);
      vlf[nf] = *(const bf16x8*)(vb_l + (size_t)(nf * 16) * kN + j0);
    }
    bf16x8 ph8, pl8;
    float f;
    {
      const float* srow = &Ss[(h * 16 + col) * SSTR + g * 8];
      float4 v0 = *(const float4*)(srow);
      float4 v1 = *(const float4*)(srow + 4);
      float vals[8] = {v0.x, v0.y, v0.z, v0.w, v1.x, v1.y, v1.z, v1.w};
      float mx = vals[0];
#pragma unroll
      for (int q = 1; q < 8; ++q) mx = fmaxf(mx, vals[q]);
      mx = fmaxf(mx, __shfl_xor(mx, 16));
      mx = fmaxf(mx, __shfl_xor(mx, 32));
      const float Mn = fmaxf(mreg, mx);
      f = __expf(mreg - Mn);
      float s = 0.f;
      float pv[8];
#pragma unroll
      for (int q = 0; q < 8; ++q) {
        pv[q] = __expf(vals[q] - Mn);
        s += pv[q];
      }
      s += __shfl_xor(s, 16);
      s += __shfl_xor(s, 32);
      lreg = lreg * f + s;
      mreg = Mn;
#pragma unroll
      for (int q = 0; q < 8; ++q) {
        unsigned short hi2, lo2;
        bf16_split(pv[q], hi2, lo2);
        ph8[q] = (short)hi2;
        pl8[q] = (short)lo2;
      }
    }
    // ---- D: PV (rescale factors via shuffle; O += P@V hi/lo 3-term) ----
    {
      float fr[4];
#pragma unroll
      for (int r = 0; r < 4; ++r) fr[r] = __shfl(f, g * 4 + r);
#pragma unroll
      for (int nf = 0; nf < 4; ++nf) {
        f32x4 a = oacc[nf];
#pragma unroll
        for (int r = 0; r < 4; ++r) a[r] *= fr[r];
        a = mfma16(ph8, vhf[nf], a);
        a = mfma16(pl8, vhf[nf], a);
        a = mfma16(ph8, vlf[nf], a);
        oacc[nf] = a;
      }
    }
  }
  // ---- epilogue: (m,l) + unnormalized O ----
  if (g == 0)
    ml[((size_t)sId * 16 + bh) * kN + (i0 + col)] = make_float2(mreg, lreg);
#pragma unroll
  for (int r = 0; r < 4; ++r) {
    float* dst = opart + ((size_t)bI * kN + i0 + g * 4 + r) * 512 + h * 64;
#pragma unroll
    for (int nf = 0; nf < 4; ++nf)
      dst[nf * 16 + col] = oacc[nf][r];
  }
}

// ---------------- K3b: combine split partials -> AO ----------------
__global__ __launch_bounds__(256) void k_combine(
    const float* __restrict__ op0, const float* __restrict__ op1,
    const float* __restrict__ op2, const float* __restrict__ op3,
    const float2* __restrict__ ml, int S, float* __restrict__ ao) {
  const size_t e = ((size_t)blockIdx.x * 256 + threadIdx.x) * 4;
  const int row = (int)(e >> 9);
  const int col = (int)(e & 511);
  const int h = col >> 6;
  const int bI = row >> 11;
  const int n = row & 2047;
  const size_t mlBase = (size_t)(bI * 8 + h) * kN + n;
  float m0 = ml[mlBase].x;
  float ms = m0;
  if (S > 1) ms = fmaxf(ms, ml[(size_t)16 * kN + mlBase].x);
  if (S > 2) {
    ms = fmaxf(ms, ml[(size_t)32 * kN + mlBase].x);
    ms = fmaxf(ms, ml[(size_t)48 * kN + mlBase].x);
  }
  const float* ops[4] = {op0, op1, op2, op3};
  float L = 0.f;
  float4 acc = make_float4(0.f, 0.f, 0.f, 0.f);
  for (int s = 0; s < S; ++s) {
    float2 v = ml[(size_t)s * 16 * kN + mlBase];
    float wgt = __expf(v.x - ms);
    L += v.y * wgt;
    float4 o4 = *(const float4*)(ops[s] + e);
    acc.x += o4.x * wgt; acc.y += o4.y * wgt;
    acc.z += o4.z * wgt; acc.w += o4.w * wgt;
  }
  float inv = 1.0f / L;
  *(float4*)(ao + e) = make_float4(acc.x * inv, acc.y * inv, acc.z * inv, acc.w * inv);
}

// ---------------- K4: out projection [4096,512]x[512,512] + bias ----------------
__global__ __launch_bounds__(256) void k_gemm_out(const float* __restrict__ a,
    const float* __restrict__ w, const float* __restrict__ bias,
    float* __restrict__ out) {
  __shared__ float As[16][68];
  __shared__ float Bs[16][68];
  const int t = threadIdx.x;
  const int colBase = blockIdx.x * 64;
  const int rowBase = blockIdx.y * 64;
  const int ti = t >> 4, tj = t & 15;
  const int ar = t >> 2, ak = (t & 3) * 4;
  const int bk = t >> 4, bc = (t & 15) * 4;
  float acc[4][4] = {};
  for (int kt = 0; kt < 512; kt += 16) {
    float4 av = *(const float4*)(a + (size_t)(rowBase + ar) * 512 + kt + ak);
    float4 wv = *(const float4*)(w + (size_t)(kt + bk) * 512 + colBase + bc);
    As[ak + 0][ar] = av.x;
    As[ak + 1][ar] = av.y;
    As[ak + 2][ar] = av.z;
    As[ak + 3][ar] = av.w;
    *(float4*)&Bs[bk][bc] = wv;
    __syncthreads();
#pragma unroll
    for (int kk = 0; kk < 16; ++kk) {
      float4 a4 = *(const float4*)&As[kk][ti * 4];
      float4 b4 = *(const float4*)&Bs[kk][tj * 4];
      float aa[4] = {a4.x, a4.y, a4.z, a4.w};
      float bb2[4] = {b4.x, b4.y, b4.z, b4.w};
#pragma unroll
      for (int r = 0; r < 4; ++r)
#pragma unroll
        for (int c = 0; c < 4; ++c)
          acc[r][c] += aa[r] * bb2[c];
    }
    __syncthreads();
  }
  float4 bias4 = *(const float4*)(bias + colBase + tj * 4);
#pragma unroll
  for (int r = 0; r < 4; ++r) {
    int row = rowBase + ti * 4 + r;
    float4 vv = make_float4(acc[r][0] + bias4.x, acc[r][1] + bias4.y,
                            acc[r][2] + bias4.z, acc[r][3] + bias4.w);
    *(float4*)(out + (size_t)row * 512 + colBase + tj * 4) = vv;
  }
}

extern "C" void kernel_launch(void* const* d_in, const int* in_sizes, int n_in,
                              void* d_out, int out_size, void* d_ws, size_t ws_size,
                              hipStream_t stream) {
  (void)in_sizes; (void)n_in; (void)out_size;
  const float* x    = (const float*)d_in[0];
  const float* sph  = (const float*)d_in[1];
  const float* g    = (const float*)d_in[2];
  const float* bta  = (const float*)d_in[3];
  const float* wqkv = (const float*)d_in[4];
  const float* wout = (const float*)d_in[5];
  const float* bout = (const float*)d_in[6];
  float* out = (float*)d_out;
  char* ws = (char*)d_ws;

  unsigned short* qhi  = (unsigned short*)(ws + OFF_QHI);
  unsigned short* qlo  = (unsigned short*)(ws + OFF_QLO);
  unsigned short* khi  = (unsigned short*)(ws + OFF_KHI);
  unsigned short* klo  = (unsigned short*)(ws + OFF_KLO);
  unsigned short* vthi = (unsigned short*)(ws + OFF_VTHI);
  unsigned short* vtlo = (unsigned short*)(ws + OFF_VTLO);
  unsigned short* vnhi = (unsigned short*)(ws + OFF_VNHI);
  unsigned short* vnlo = (unsigned short*)(ws + OFF_VNLO);
  float2* ml = (float2*)(ws + OFF_ML);
  float* mu = (float*)(ws + OFF_MU);
  float* rs = (float*)(ws + OFF_RS);

  // runtime split selection by ws_size (deterministic: ws_size is constant)
  int S;
  if      (ws_size >= (73u << 20)) S = 4;
  else if (ws_size >= (55u << 20)) S = 2;
  else                             S = 1;
  float* ao = (float*)(ws + ((ws_size >= (46u << 20)) ? OFF_AO_BIG : OFF_AO_SMALL));
  float* op0 = ao;
  float* op1 = (S > 1) ? (float*)(ws + OFF_OP1) : ao;
  float* op2 = (S > 2) ? (float*)(ws + OFF_OP1 + (9u << 20)) : ao;
  float* op3 = (S > 3) ? (float*)(ws + OFF_OP1 + (18u << 20)) : ao;
  const int jLen = kN / S;

  k_ln_stats<<<dim3(1024), dim3(256), 0, stream>>>(x, mu, rs);
  k_gemm_qkv<<<dim3(24, 64), dim3(256), 0, stream>>>(x, mu, rs, g, bta, wqkv,
                                                     qhi, qlo, khi, klo, vnhi, vnlo);
  k_vtrans<<<dim3(1024), dim3(256), 0, stream>>>(vnhi, vnlo, vthi, vtlo);
  k_attn<<<dim3(256 * S), dim3(512), 0, stream>>>(qhi, qlo, khi, klo, vthi, vtlo,
                                                  sph, op0, op1, op2, op3, ml, jLen);
  k_combine<<<dim3(2048), dim3(256), 0, stream>>>(op0, op1, op2, op3, ml, S, ao);
  k_gemm_out<<<dim3(8, 64), dim3(256), 0, stream>>>(ao, wout, bout, out);
}

// Round 6
// 277.828 us; speedup vs baseline: 1.5276x; 1.3635x over previous
//
#include <hip/hip_runtime.h>
#include <math.h>

// GlobalSphereAttention: LN -> QKV -> per-head dots * scale * (1+sph)
//   -> cross-head mean/std(ddof=1) normalize -> softmax(j) -> PV -> out proj.
// B=2, N=2048, DIM=512, HEADS=8, DHEAD=64.
// Round 6: Q-tile 64 (4x K/V traffic reduction; L3-path was saturated at
// ~8 TB/s). 512-thr blocks, wave=head, 4 row-blocks/wave, j-tile 32,
// P in registers, 2 barriers/tile, split-j S by ws_size, in-place combine.

typedef __attribute__((ext_vector_type(8))) short bf16x8;
typedef __attribute__((ext_vector_type(8))) unsigned short u16x8;
typedef __attribute__((ext_vector_type(4))) float f32x4;

constexpr int kDim = 512;
constexpr int kN = 2048;
constexpr float kEps = 1e-5f;
constexpr float kScale = 0.125f; // 64^-0.5

// ws layout (byte offsets): 6 planes (24MB) + op partials (8MB each) + ml + mu/rs
constexpr size_t OFF_QHI  = 0;
constexpr size_t OFF_QLO  = 4u << 20;
constexpr size_t OFF_KHI  = 8u << 20;
constexpr size_t OFF_KLO  = 12u << 20;
constexpr size_t OFF_VTHI = 16u << 20;  // transposed [bh][d][n]
constexpr size_t OFF_VTLO = 20u << 20;
constexpr size_t OFF_OP   = 24u << 20;  // op_s = OP + s*8MB; op0 aliases VN
constexpr size_t OFF_VNHI = 24u << 20;  // natural V (dead after vtrans)
constexpr size_t OFF_VNLO = 28u << 20;
constexpr size_t OP_STRIDE = 2097152;   // floats per partial (8 MiB)

__device__ __forceinline__ void bf16_split(float x, unsigned short& hi,
                                           unsigned short& lo) {
  unsigned int u = __float_as_uint(x);
  hi = (unsigned short)(u >> 16);
  float r = x - __uint_as_float(u & 0xffff0000u);  // exact
  lo = (unsigned short)(__float_as_uint(r) >> 16);
}
__device__ __forceinline__ f32x4 mfma16(bf16x8 a, bf16x8 b, f32x4 c) {
  return __builtin_amdgcn_mfma_f32_16x16x32_bf16(a, b, c, 0, 0, 0);
}

// ---------------- K1: LayerNorm row stats ----------------
__global__ __launch_bounds__(256) void k_ln_stats(const float* __restrict__ x,
                                                  float* __restrict__ mu,
                                                  float* __restrict__ rs) {
  int row = blockIdx.x * 4 + (threadIdx.x >> 6);
  int lane = threadIdx.x & 63;
  const float4* xr = (const float4*)(x + (size_t)row * kDim + lane * 8);
  float4 a = xr[0], b = xr[1];
  float s = a.x + a.y + a.z + a.w + b.x + b.y + b.z + b.w;
  float q = a.x*a.x + a.y*a.y + a.z*a.z + a.w*a.w
          + b.x*b.x + b.y*b.y + b.z*b.z + b.w*b.w;
#pragma unroll
  for (int off = 32; off > 0; off >>= 1) {
    s += __shfl_down(s, off);
    q += __shfl_down(q, off);
  }
  if (lane == 0) {
    float m = s * (1.0f / kDim);
    float v = q * (1.0f / kDim) - m * m;
    mu[row] = m;
    rs[row] = 1.0f / sqrtf(v + kEps);
  }
}

// ---------------- K2: fused-LN QKV GEMM, epilogue -> bf16 hi/lo planes ------
__global__ __launch_bounds__(256) void k_gemm_qkv(const float* __restrict__ x,
    const float* __restrict__ mu, const float* __restrict__ rs,
    const float* __restrict__ g, const float* __restrict__ bta,
    const float* __restrict__ w,
    unsigned short* __restrict__ qhi, unsigned short* __restrict__ qlo,
    unsigned short* __restrict__ khi, unsigned short* __restrict__ klo,
    unsigned short* __restrict__ vnhi, unsigned short* __restrict__ vnlo) {
  __shared__ float As[16][68];  // A^T tile (k-major)
  __shared__ float Bs[16][68];
  const int t = threadIdx.x;
  const int colBase = blockIdx.x * 64;
  const int rowBase = blockIdx.y * 64;
  const int ti = t >> 4, tj = t & 15;
  const int ar = t >> 2, ak = (t & 3) * 4;
  const int bk = t >> 4, bc = (t & 15) * 4;
  const int arow = rowBase + ar;
  const float amu = mu[arow], ars = rs[arow];
  float acc[4][4] = {};
  for (int kt = 0; kt < kDim; kt += 16) {
    float4 av = *(const float4*)(x + (size_t)arow * kDim + kt + ak);
    float4 gv = *(const float4*)(g + kt + ak);
    float4 bv = *(const float4*)(bta + kt + ak);
    float4 wv = *(const float4*)(w + (size_t)(kt + bk) * 1536 + colBase + bc);
    As[ak + 0][ar] = (av.x - amu) * ars * gv.x + bv.x;
    As[ak + 1][ar] = (av.y - amu) * ars * gv.y + bv.y;
    As[ak + 2][ar] = (av.z - amu) * ars * gv.z + bv.z;
    As[ak + 3][ar] = (av.w - amu) * ars * gv.w + bv.w;
    *(float4*)&Bs[bk][bc] = wv;
    __syncthreads();
#pragma unroll
    for (int kk = 0; kk < 16; ++kk) {
      float4 a4 = *(const float4*)&As[kk][ti * 4];
      float4 b4 = *(const float4*)&Bs[kk][tj * 4];
      float aa[4] = {a4.x, a4.y, a4.z, a4.w};
      float bb2[4] = {b4.x, b4.y, b4.z, b4.w};
#pragma unroll
      for (int r = 0; r < 4; ++r)
#pragma unroll
        for (int c = 0; c < 4; ++c)
          acc[r][c] += aa[r] * bb2[c];
    }
    __syncthreads();
  }
  const int col0 = colBase + tj * 4;
  const int which = col0 >> 9;
  const int cc = col0 & 511;
  const int h = cc >> 6, d = cc & 63;
  unsigned short* ph = (which == 0) ? qhi : ((which == 1) ? khi : vnhi);
  unsigned short* pl = (which == 0) ? qlo : ((which == 1) ? klo : vnlo);
#pragma unroll
  for (int r = 0; r < 4; ++r) {
    int row = rowBase + ti * 4 + r;
    int bI = row >> 11, n = row & 2047;
    size_t base = ((size_t)(bI * 8 + h) * kN + n) * 64 + d;
    unsigned short hv[4], lv[4];
#pragma unroll
    for (int c = 0; c < 4; ++c) bf16_split(acc[r][c], hv[c], lv[c]);
    *(ushort4*)(ph + base) = make_ushort4(hv[0], hv[1], hv[2], hv[3]);
    *(ushort4*)(pl + base) = make_ushort4(lv[0], lv[1], lv[2], lv[3]);
  }
}

// ---------------- K2b: V transpose [bh][n][64] -> [bh][d][n] ----------------
__global__ __launch_bounds__(256) void k_vtrans(
    const unsigned short* __restrict__ vnhi, const unsigned short* __restrict__ vnlo,
    unsigned short* __restrict__ vthi, unsigned short* __restrict__ vtlo) {
  __shared__ unsigned short tile[64][72];
  const int id = blockIdx.x;
  const int p = id >> 9;
  const int bh = (id >> 5) & 15;
  const int nt = id & 31;
  const unsigned short* src = (p ? vnlo : vnhi) + ((size_t)bh * kN + nt * 64) * 64;
  unsigned short* dst = (p ? vtlo : vthi) + (size_t)bh * 64 * kN + nt * 64;
  const int r = threadIdx.x >> 3;
  const int c = (threadIdx.x & 7) * 8;
#pragma unroll
  for (int rr = 0; rr < 64; rr += 32) {
    u16x8 v = *(const u16x8*)(src + (size_t)(r + rr) * 64 + c);
    *(u16x8*)&tile[r + rr][c] = v;
  }
  __syncthreads();
#pragma unroll
  for (int dd = 0; dd < 64; dd += 32) {
    int d = r + dd;
    u16x8 v;
#pragma unroll
    for (int e = 0; e < 8; ++e) v[e] = tile[c + e][d];
    *(u16x8*)(dst + (size_t)d * kN + c) = v;
  }
}

// ---------------- K3: fused sphere attention, Q-tile 64 ----------------
// grid = 64*S blocks x 512 threads (8 waves; wave=head; 4 row-blocks/wave).
__global__ __launch_bounds__(512, 2) void k_attn(
    const unsigned short* __restrict__ qhi, const unsigned short* __restrict__ qlo,
    const unsigned short* __restrict__ khi, const unsigned short* __restrict__ klo,
    const unsigned short* __restrict__ vthi, const unsigned short* __restrict__ vtlo,
    const float* __restrict__ sph, float* __restrict__ op,
    float2* __restrict__ ml, int jLen) {
  constexpr int SSTR = 33;            // dwords/row
  __shared__ float Ss[512 * SSTR];    // 67.6 KB: row = h*64 + i (i in 0..63)

  const int t = threadIdx.x;
  const int h = t >> 6;
  const int lane = t & 63;
  const int col = lane & 15;
  const int g = lane >> 4;
  const int tileId = blockIdx.x & 63;
  const int sId = blockIdx.x >> 6;
  const int bI = tileId >> 5;
  const int i0 = (tileId & 31) << 6;
  const int jStart = sId * jLen;
  const int jEnd = (jStart + jLen < kN) ? (jStart + jLen) : kN;
  const size_t bh = (size_t)bI * 8 + h;
  float* opart = op + (size_t)sId * OP_STRIDE;

  // persistent Q fragments: 4 row-blocks x 2 d-chunks x hi/lo
  bf16x8 qhf[4][2], qlf[4][2];
#pragma unroll
  for (int rb = 0; rb < 4; ++rb) {
    const size_t qoff = (bh * kN + i0 + rb * 16 + col) * 64 + g * 8;
    qhf[rb][0] = *(const bf16x8*)(qhi + qoff);
    qhf[rb][1] = *(const bf16x8*)(qhi + qoff + 32);
    qlf[rb][0] = *(const bf16x8*)(qlo + qoff);
    qlf[rb][1] = *(const bf16x8*)(qlo + qoff + 32);
  }
  const unsigned short* kb_h = khi + (bh * kN + col) * 64 + g * 8;
  const unsigned short* kb_l = klo + (bh * kN + col) * 64 + g * 8;
  const unsigned short* vb_h = vthi + (bh * 64 + col) * kN + g * 8;
  const unsigned short* vb_l = vtlo + (bh * 64 + col) * kN + g * 8;

  // norm-phase ownership: thread -> (row iN, 4 j's at jN)
  const int iN = t >> 3;
  const int jN = (t & 7) * 4;
  const float* sphp = sph + (size_t)(i0 + iN) * kN + jN;
  float4 sphc = *(const float4*)(sphp + jStart);

  f32x4 oacc[4][4];
#pragma unroll
  for (int rb = 0; rb < 4; ++rb)
#pragma unroll
    for (int nf = 0; nf < 4; ++nf) oacc[rb][nf] = (f32x4){0.f, 0.f, 0.f, 0.f};
  float mreg[4] = {-INFINITY, -INFINITY, -INFINITY, -INFINITY};
  float lreg[4] = {0.f, 0.f, 0.f, 0.f};

  for (int j0 = jStart; j0 < jEnd; j0 += 32) {
    // ---- A: QK^T, 4 row-blocks share one K-tile (hi/lo 3-term) ----
    {
      const size_t ko = (size_t)j0 * 64;
      bf16x8 kh[2][2], kl[2][2];
#pragma unroll
      for (int jf = 0; jf < 2; ++jf)
#pragma unroll
        for (int c = 0; c < 2; ++c) {
          kh[jf][c] = *(const bf16x8*)(kb_h + ko + jf * 1024 + c * 32);
          kl[jf][c] = *(const bf16x8*)(kb_l + ko + jf * 1024 + c * 32);
        }
#pragma unroll
      for (int rb = 0; rb < 4; ++rb)
#pragma unroll
        for (int jf = 0; jf < 2; ++jf) {
          f32x4 a = (f32x4){0.f, 0.f, 0.f, 0.f};
          a = mfma16(qhf[rb][0], kh[jf][0], a);
          a = mfma16(qhf[rb][1], kh[jf][1], a);
          a = mfma16(qlf[rb][0], kh[jf][0], a);
          a = mfma16(qlf[rb][1], kh[jf][1], a);
          a = mfma16(qhf[rb][0], kl[jf][0], a);
          a = mfma16(qhf[rb][1], kl[jf][1], a);
#pragma unroll
          for (int r = 0; r < 4; ++r)
            Ss[(h * 64 + rb * 16 + g * 4 + r) * SSTR + jf * 16 + col] = a[r];
        }
    }
    // ---- issue V loads early (land during B/C) ----
    bf16x8 vhf[4], vlf[4];
#pragma unroll
    for (int nf = 0; nf < 4; ++nf) {
      vhf[nf] = *(const bf16x8*)(vb_h + (size_t)(nf * 16) * kN + j0);
      vlf[nf] = *(const bf16x8*)(vb_l + (size_t)(nf * 16) * kN + j0);
    }
    __syncthreads();
    // ---- B: cross-head normalization (4 (i,j) per thread, vectorized) ----
    {
      const int jn = (j0 + 32 < jEnd) ? (j0 + 32) : j0;
      const float4 sphn = *(const float4*)(sphp + jn);  // prefetch next
      const float m4[4] = {kScale * (1.0f + sphc.x), kScale * (1.0f + sphc.y),
                           kScale * (1.0f + sphc.z), kScale * (1.0f + sphc.w)};
      float dv[8][4];
#pragma unroll
      for (int hh = 0; hh < 8; ++hh) {
        float4 v = *(const float4*)&Ss[(hh * 64 + iN) * SSTR + jN];
        dv[hh][0] = v.x * m4[0]; dv[hh][1] = v.y * m4[1];
        dv[hh][2] = v.z * m4[2]; dv[hh][3] = v.w * m4[3];
      }
#pragma unroll
      for (int jj = 0; jj < 4; ++jj) {
        float s = 0.f;
#pragma unroll
        for (int hh = 0; hh < 8; ++hh) s += dv[hh][jj];
        const float mean = s * 0.125f;
        float var = 0.f;
#pragma unroll
        for (int hh = 0; hh < 8; ++hh) {
          float d = dv[hh][jj] - mean;
          var += d * d;
        }
        const float inv = rsqrtf(var * (1.0f / 7.0f));
#pragma unroll
        for (int hh = 0; hh < 8; ++hh) dv[hh][jj] = (dv[hh][jj] - mean) * inv;
      }
#pragma unroll
      for (int hh = 0; hh < 8; ++hh) {
        float4 v = make_float4(dv[hh][0], dv[hh][1], dv[hh][2], dv[hh][3]);
        *(float4*)&Ss[(hh * 64 + iN) * SSTR + jN] = v;
      }
      sphc = sphn;
    }
    __syncthreads();
    // ---- C: online softmax per row-block; P packed to registers ----
    bf16x8 ph[4], pl[4];
    float fx[4];
#pragma unroll
    for (int rb = 0; rb < 4; ++rb) {
      const float* srow = &Ss[(h * 64 + rb * 16 + col) * SSTR + g * 8];
      float4 v0 = *(const float4*)(srow);
      float4 v1 = *(const float4*)(srow + 4);
      float vals[8] = {v0.x, v0.y, v0.z, v0.w, v1.x, v1.y, v1.z, v1.w};
      float mx = vals[0];
#pragma unroll
      for (int q = 1; q < 8; ++q) mx = fmaxf(mx, vals[q]);
      mx = fmaxf(mx, __shfl_xor(mx, 16));
      mx = fmaxf(mx, __shfl_xor(mx, 32));
      const float Mn = fmaxf(mreg[rb], mx);
      const float f = __expf(mreg[rb] - Mn);
      float s = 0.f;
      float pv[8];
#pragma unroll
      for (int q = 0; q < 8; ++q) {
        pv[q] = __expf(vals[q] - Mn);
        s += pv[q];
      }
      s += __shfl_xor(s, 16);
      s += __shfl_xor(s, 32);
      lreg[rb] = lreg[rb] * f + s;
      mreg[rb] = Mn;
      fx[rb] = f;
#pragma unroll
      for (int q = 0; q < 8; ++q) {
        unsigned short hi2, lo2;
        bf16_split(pv[q], hi2, lo2);
        ph[rb][q] = (short)hi2;
        pl[rb][q] = (short)lo2;
      }
    }
    // ---- D: PV, 4 row-blocks share one V-tile (no barrier; regs only) ----
#pragma unroll
    for (int rb = 0; rb < 4; ++rb) {
      float fr[4];
#pragma unroll
      for (int r = 0; r < 4; ++r) fr[r] = __shfl(fx[rb], g * 4 + r);
#pragma unroll
      for (int nf = 0; nf < 4; ++nf) {
        f32x4 a = oacc[rb][nf];
#pragma unroll
        for (int r = 0; r < 4; ++r) a[r] *= fr[r];
        a = mfma16(ph[rb], vhf[nf], a);
        a = mfma16(pl[rb], vhf[nf], a);
        a = mfma16(ph[rb], vlf[nf], a);
        oacc[rb][nf] = a;
      }
    }
  }
  // ---- epilogue: (m,l) + unnormalized O ----
#pragma unroll
  for (int rb = 0; rb < 4; ++rb) {
    if (g == 0)
      ml[((size_t)sId * 16 + bh) * kN + (i0 + rb * 16 + col)] =
          make_float2(mreg[rb], lreg[rb]);
#pragma unroll
    for (int r = 0; r < 4; ++r) {
      float* dst = opart + ((size_t)bI * kN + i0 + rb * 16 + g * 4 + r) * 512 + h * 64;
#pragma unroll
      for (int nf = 0; nf < 4; ++nf)
        dst[nf * 16 + col] = oacc[rb][nf][r];
    }
  }
}

// ---------------- K3b: combine split partials in place into op0 ----------------
__global__ __launch_bounds__(256) void k_combine(float* __restrict__ op,
    const float2* __restrict__ ml, int S) {
  const size_t e = ((size_t)blockIdx.x * 256 + threadIdx.x) * 4;
  const int row = (int)(e >> 9);
  const int col = (int)(e & 511);
  const int h = col >> 6;
  const int bI = row >> 11;
  const int n = row & 2047;
  const size_t mlBase = (size_t)(bI * 8 + h) * kN + n;
  float ms = -INFINITY;
  for (int s = 0; s < S; ++s)
    ms = fmaxf(ms, ml[(size_t)s * 16 * kN + mlBase].x);
  float L = 0.f;
  float4 acc = make_float4(0.f, 0.f, 0.f, 0.f);
  for (int s = 0; s < S; ++s) {
    float2 v = ml[(size_t)s * 16 * kN + mlBase];
    float wgt = __expf(v.x - ms);
    L += v.y * wgt;
    float4 o4 = *(const float4*)(op + (size_t)s * OP_STRIDE + e);
    acc.x += o4.x * wgt; acc.y += o4.y * wgt;
    acc.z += o4.z * wgt; acc.w += o4.w * wgt;
  }
  float inv = 1.0f / L;
  *(float4*)(op + e) = make_float4(acc.x * inv, acc.y * inv,
                                   acc.z * inv, acc.w * inv);
}

// ---------------- K4: out projection [4096,512]x[512,512] + bias ----------------
__global__ __launch_bounds__(256) void k_gemm_out(const float* __restrict__ a,
    const float* __restrict__ w, const float* __restrict__ bias,
    float* __restrict__ out) {
  __shared__ float As[16][68];
  __shared__ float Bs[16][68];
  const int t = threadIdx.x;
  const int colBase = blockIdx.x * 64;
  const int rowBase = blockIdx.y * 64;
  const int ti = t >> 4, tj = t & 15;
  const int ar = t >> 2, ak = (t & 3) * 4;
  const int bk = t >> 4, bc = (t & 15) * 4;
  float acc[4][4] = {};
  for (int kt = 0; kt < 512; kt += 16) {
    float4 av = *(const float4*)(a + (size_t)(rowBase + ar) * 512 + kt + ak);
    float4 wv = *(const float4*)(w + (size_t)(kt + bk) * 512 + colBase + bc);
    As[ak + 0][ar] = av.x;
    As[ak + 1][ar] = av.y;
    As[ak + 2][ar] = av.z;
    As[ak + 3][ar] = av.w;
    *(float4*)&Bs[bk][bc] = wv;
    __syncthreads();
#pragma unroll
    for (int kk = 0; kk < 16; ++kk) {
      float4 a4 = *(const float4*)&As[kk][ti * 4];
      float4 b4 = *(const float4*)&Bs[kk][tj * 4];
      float aa[4] = {a4.x, a4.y, a4.z, a4.w};
      float bb2[4] = {b4.x, b4.y, b4.z, b4.w};
#pragma unroll
      for (int r = 0; r < 4; ++r)
#pragma unroll
        for (int c = 0; c < 4; ++c)
          acc[r][c] += aa[r] * bb2[c];
    }
    __syncthreads();
  }
  float4 bias4 = *(const float4*)(bias + colBase + tj * 4);
#pragma unroll
  for (int r = 0; r < 4; ++r) {
    int row = rowBase + ti * 4 + r;
    float4 vv = make_float4(acc[r][0] + bias4.x, acc[r][1] + bias4.y,
                            acc[r][2] + bias4.z, acc[r][3] + bias4.w);
    *(float4*)(out + (size_t)row * 512 + colBase + tj * 4) = vv;
  }
}

extern "C" void kernel_launch(void* const* d_in, const int* in_sizes, int n_in,
                              void* d_out, int out_size, void* d_ws, size_t ws_size,
                              hipStream_t stream) {
  (void)in_sizes; (void)n_in; (void)out_size;
  const float* x    = (const float*)d_in[0];
  const float* sph  = (const float*)d_in[1];
  const float* g    = (const float*)d_in[2];
  const float* bta  = (const float*)d_in[3];
  const float* wqkv = (const float*)d_in[4];
  const float* wout = (const float*)d_in[5];
  const float* bout = (const float*)d_in[6];
  float* out = (float*)d_out;
  char* ws = (char*)d_ws;

  unsigned short* qhi  = (unsigned short*)(ws + OFF_QHI);
  unsigned short* qlo  = (unsigned short*)(ws + OFF_QLO);
  unsigned short* khi  = (unsigned short*)(ws + OFF_KHI);
  unsigned short* klo  = (unsigned short*)(ws + OFF_KLO);
  unsigned short* vthi = (unsigned short*)(ws + OFF_VTHI);
  unsigned short* vtlo = (unsigned short*)(ws + OFF_VTLO);
  unsigned short* vnhi = (unsigned short*)(ws + OFF_VNHI);
  unsigned short* vnlo = (unsigned short*)(ws + OFF_VNLO);
  float* op = (float*)(ws + OFF_OP);

  // split count by available ws: need 24MB planes + S*8MB + S*256KB + 32KB
  int S, jLen;
  if      (ws_size >= (59u << 20)) { S = 4; jLen = 512;  }
  else if (ws_size >= (51u << 20)) { S = 3; jLen = 704;  }
  else if (ws_size >= (43u << 20)) { S = 2; jLen = 1024; }
  else                             { S = 1; jLen = 2048; }
  float2* ml = (float2*)(ws + OFF_OP + (size_t)S * OP_STRIDE * 4);
  float* mu  = (float*)((char*)ml + (size_t)S * 16 * kN * 8);
  float* rs  = mu + 4096;

  k_ln_stats<<<dim3(1024), dim3(256), 0, stream>>>(x, mu, rs);
  k_gemm_qkv<<<dim3(24, 64), dim3(256), 0, stream>>>(x, mu, rs, g, bta, wqkv,
                                                     qhi, qlo, khi, klo, vnhi, vnlo);
  k_vtrans<<<dim3(1024), dim3(256), 0, stream>>>(vnhi, vnlo, vthi, vtlo);
  k_attn<<<dim3(64 * S), dim3(512), 0, stream>>>(qhi, qlo, khi, klo, vthi, vtlo,
                                                 sph, op, ml, jLen);
  k_combine<<<dim3(2048), dim3(256), 0, stream>>>(op, ml, S);
  k_gemm_out<<<dim3(8, 64), dim3(256), 0, stream>>>(op, wout, bout, out);
}